// Round 14
// baseline (1169.052 us; speedup 1.0000x reference)
//
#include <hip/hip_runtime.h>
#include <hip/hip_fp16.h>

#define NN 65536
#define EE 524288
#define EPX 589824   // EE + NN
#define GG 1024
#define NSLOT 64     // BN stat slot copies (breaks atomic contention)

typedef __attribute__((ext_vector_type(8))) short bf16x8;
typedef __attribute__((ext_vector_type(4))) float f32x4;

#define LOG2E 1.44269504088896f

// ---------------- bf16/f16 helpers ----------------

__device__ __forceinline__ unsigned short f2bf(float x) {
    unsigned int u = __float_as_uint(x);
    u += 0x7FFFu + ((u >> 16) & 1u);      // round-to-nearest-even
    return (unsigned short)(u >> 16);
}
__device__ __forceinline__ float bflo(unsigned int w) { return __uint_as_float(w << 16); }
__device__ __forceinline__ float bfhi(unsigned int w) { return __uint_as_float(w & 0xFFFF0000u); }
__device__ __forceinline__ float bf2f(unsigned short u) { return __uint_as_float((unsigned int)u << 16); }
__device__ __forceinline__ float lrelu(float x) { return fmaf(0.4f, fabsf(x), 0.6f * x); }
__device__ __forceinline__ unsigned int packh2(float a, float b) {
    __half2 h = __floats2half2_rn(a, b);
    return *reinterpret_cast<unsigned int*>(&h);
}
__device__ __forceinline__ unsigned long long rfl64(unsigned long long v) {
    unsigned int lo = __builtin_amdgcn_readfirstlane((unsigned int)v);
    unsigned int hi = __builtin_amdgcn_readfirstlane((unsigned int)(v >> 32));
    return (((unsigned long long)hi) << 32) | lo;
}

// DPP-based in-row reduce: sum over each 16-lane row, result in all 16 lanes. Pure VALU.
template <int CTRL>
__device__ __forceinline__ float dpp_add(float v) {
    int x = __builtin_amdgcn_update_dpp(0, __float_as_int(v), CTRL, 0xf, 0xf, true);
    return v + __int_as_float(x);
}
__device__ __forceinline__ float head_reduce(float t) {
    t = dpp_add<0xB1>(t);    // quad_perm [1,0,3,2]  (xor 1)
    t = dpp_add<0x4E>(t);    // quad_perm [2,3,0,1]  (xor 2)
    t = dpp_add<0x124>(t);   // row_ror:4
    t = dpp_add<0x128>(t);   // row_ror:8  -> full 16-lane sum
    return t;
}

// ---------------- CSR build ----------------

__launch_bounds__(256)
__global__ void k_deg(const int* __restrict__ dst0, int* __restrict__ deg)
{
    int e = blockIdx.x * 256 + threadIdx.x;
    if (e >= EE) return;
    atomicAdd(&deg[dst0[e]], 1);
}

__launch_bounds__(1024)
__global__ void k_scan(const int* __restrict__ deg, int* __restrict__ rowptr)
{
    __shared__ int sums[1024];
    int t = threadIdx.x;
    int base = t * 64;
    int s = 0;
    for (int i = 0; i < 64; i++) s += deg[base + i] + 1;
    sums[t] = s;
    __syncthreads();
    for (int off = 1; off < 1024; off <<= 1) {
        int v = (t >= off) ? sums[t - off] : 0;
        __syncthreads();
        sums[t] += v;
        __syncthreads();
    }
    int off = sums[t] - s;   // exclusive prefix
    for (int i = 0; i < 64; i++) { rowptr[base + i] = off; off += deg[base + i] + 1; }
    if (t == 1023) rowptr[NN] = off;
}

// scatter edges into CSR order; attrs -> f16 padded 32B/edge; csr_src/csr_dst byte offsets;
// csr_eid = original edge id (-1 for self-loop).
__launch_bounds__(256)
__global__ void k_scatter(const int* __restrict__ src0, const int* __restrict__ dst0,
                          const float* __restrict__ eattr,
                          const int* __restrict__ rowptr, const int* __restrict__ deg,
                          int* __restrict__ fill, int* __restrict__ csr_src,
                          int* __restrict__ csr_dst, int* __restrict__ csr_eid,
                          unsigned short* __restrict__ eaCSR)
{
    int e = blockIdx.x * 256 + threadIdx.x;
    if (e >= EPX) return;
    if (e < EE) {
        int d = dst0[e];
        int pos = rowptr[d] + atomicAdd(&fill[d], 1);
        csr_src[pos] = src0[e] << 8;   // byte offset into bf16 row (128*2B)
        csr_dst[pos] = d << 8;
        csr_eid[pos] = e;
        const float* ep = eattr + (size_t)e * 12;
        float4 a = *reinterpret_cast<const float4*>(ep);
        float4 b = *reinterpret_cast<const float4*>(ep + 4);
        float4 c = *reinterpret_cast<const float4*>(ep + 8);
        unsigned short* o = eaCSR + (size_t)pos * 16;
        uint4 w; w.x = packh2(a.x, a.y); w.y = packh2(a.z, a.w);
        w.z = packh2(b.x, b.y); w.w = packh2(b.z, b.w);
        *reinterpret_cast<uint4*>(o) = w;
        *reinterpret_cast<uint2*>(o + 8) = make_uint2(packh2(c.x, c.y), packh2(c.z, c.w));
    } else {
        int n = e - EE;
        int pos = rowptr[n] + deg[n];   // self-loop in the last slot
        csr_src[pos] = n << 8;
        csr_dst[pos] = n << 8;
        csr_eid[pos] = -1;
    }
}

// fill each node's self-loop attr slot with the mean of its real incoming edge attrs.
__launch_bounds__(256)
__global__ void k_selfattr(const int* __restrict__ rowptr, unsigned short* __restrict__ eaCSR)
{
    int tid = blockIdx.x * 256 + threadIdx.x;   // NN*16 threads
    int n = tid >> 4;
    int lk = tid & 15;
    if (lk >= 12) return;
    int beg = rowptr[n], endm1 = rowptr[n + 1] - 1;
    float s = 0.f;
    for (int p = beg; p < endm1; ++p) {
        __half h = *reinterpret_cast<const __half*>(&eaCSR[(size_t)p * 16 + lk]);
        s += __half2float(h);
    }
    float dv = fmaxf((float)(endm1 - beg), 1.0f);
    __half ho = __float2half(s / dv);
    eaCSR[(size_t)endm1 * 16 + lk] = *reinterpret_cast<unsigned short*>(&ho);
}

// ---------------- MFMA weight prep: swizzle W into 16x16x32 B-fragment order ----------------

__launch_bounds__(256)
__global__ void k_wprep(const float* __restrict__ Wl, const float* __restrict__ Wr,
                        const float* __restrict__ Wp1,
                        unsigned short* __restrict__ wg, unsigned short* __restrict__ wp)
{
    int tid = blockIdx.x * 256 + threadIdx.x;   // 34816 threads
    if (tid < 32768) {
        int l = tid >> 12;
        int r = tid & 4095;
        int kt = r >> 10, ct = (r >> 6) & 15, lane = r & 63;
        int kb = kt * 32 + (lane >> 4) * 8;
        int col = ct * 16 + (lane & 15);
        const float* W = (col < 128) ? (Wl + (size_t)l * 16384 + col)
                                     : (Wr + (size_t)l * 16384 + (col - 128));
        unsigned short* o = wg + (size_t)tid * 8;
#pragma unroll
        for (int j = 0; j < 8; j++) o[j] = f2bf(W[(size_t)(kb + j) * 128]);
    } else if (tid < 34816) {
        int r = tid - 32768;
        int kt = r >> 9, ct = (r >> 6) & 7, lane = r & 63;
        int kb = kt * 32 + (lane >> 4) * 8;
        int col = ct * 16 + (lane & 15);
        const float* W = (col < 64) ? (Wp1 + col) : (Wp1 + 128 * 64 + (col - 64));
        unsigned short* o = wp + (size_t)r * 8;
#pragma unroll
        for (int j = 0; j < 8; j++) o[j] = f2bf(W[(size_t)(kb + j) * 64]);
    }
}

// ---------------- input layer: h = relu(x @ Win + bin) ----------------

__launch_bounds__(256)
__global__ void k_input(const float* __restrict__ x, const float* __restrict__ Win,
                        const float* __restrict__ bin, float* __restrict__ h)
{
    __shared__ float W[21 * 128];
    int t = threadIdx.x;
    for (int i = t; i < 21 * 128; i += 256) W[i] = Win[i];
    __syncthreads();
    int c = t & 127, sub = t >> 7;
    int n0 = blockIdx.x * 16;
    float bc = bin[c];
    for (int i = 0; i < 8; i++) {
        int n = n0 + sub + i * 2;
        const float* xp = x + (size_t)n * 21;
        float acc = bc;
#pragma unroll
        for (int k = 0; k < 21; k++) acc = fmaf(xp[k], W[k * 128 + c], acc);
        h[(size_t)n * 128 + c] = fmaxf(acc, 0.f);
    }
}

// ---------------- MFMA GEMMs (no LDS; A fp32 -> bf16 in-register; B pre-swizzled) ----------------

__device__ __forceinline__ void load_afrag(const float* __restrict__ A, int arow, int kb,
                                           bf16x8 af[4])
{
#pragma unroll
    for (int kt = 0; kt < 4; kt++) {
        const float* ap = A + (size_t)arow * 128 + kt * 32 + kb;
        float4 lo = *reinterpret_cast<const float4*>(ap);
        float4 hi = *reinterpret_cast<const float4*>(ap + 4);
        bf16x8 v;
        v[0] = (short)f2bf(lo.x); v[1] = (short)f2bf(lo.y);
        v[2] = (short)f2bf(lo.z); v[3] = (short)f2bf(lo.w);
        v[4] = (short)f2bf(hi.x); v[5] = (short)f2bf(hi.y);
        v[6] = (short)f2bf(hi.z); v[7] = (short)f2bf(hi.w);
        af[kt] = v;
    }
}

__device__ __forceinline__ void gemm_gat_core(const bf16x8 af[4], const unsigned short* __restrict__ Bf,
                                              int row0, unsigned short* __restrict__ Cl,
                                              unsigned short* __restrict__ Cr, int lane)
{
    int crow = row0 + (lane >> 4) * 4;
    int c0 = lane & 15;
#pragma unroll
    for (int ct = 0; ct < 16; ct++) {
        f32x4 acc = {0.f, 0.f, 0.f, 0.f};
#pragma unroll
        for (int kt = 0; kt < 4; kt++) {
            bf16x8 bf = *reinterpret_cast<const bf16x8*>(Bf + ((size_t)(kt * 16 + ct) * 64 + lane) * 8);
            acc = __builtin_amdgcn_mfma_f32_16x16x32_bf16(af[kt], bf, acc, 0, 0, 0);
        }
        int col = ct * 16 + c0;
        unsigned short* C = (col < 128) ? Cl : Cr;
        int cc = col & 127;
#pragma unroll
        for (int r = 0; r < 4; r++)
            C[(size_t)(crow + r) * 128 + cc] = f2bf(acc[r]);
    }
}

// xl|xr = h @ [Wl|Wr], plain fp32 A
__launch_bounds__(256)
__global__ void k_gemm_gat(const float* __restrict__ A, const unsigned short* __restrict__ Bf,
                           unsigned short* __restrict__ Cl, unsigned short* __restrict__ Cr)
{
    int wave = threadIdx.x >> 6, lane = threadIdx.x & 63;
    int row0 = blockIdx.x * 64 + wave * 16;
    bf16x8 af[4];
    load_afrag(A, row0 + (lane & 15), (lane >> 4) * 8, af);
    gemm_gat_core(af, Bf, row0, Cl, Cr, lane);
}

// xl|xr = relu(bn(g)) @ [Wl|Wr]: BN coeffs from slotted stats, applied on the A-load.
__launch_bounds__(256)
__global__ void k_gemm_gat_bn(const float* __restrict__ G, const float* __restrict__ bnstat,
                              const float* __restrict__ scale, const float* __restrict__ bias,
                              const unsigned short* __restrict__ Bf,
                              unsigned short* __restrict__ Cl, unsigned short* __restrict__ Cr)
{
    __shared__ float sA[128], bA[128];
    int t = threadIdx.x;
    if (t < 128) {
        float sum = 0.f, sq = 0.f;
#pragma unroll
        for (int sl = 0; sl < NSLOT; sl++) {
            sum += bnstat[sl * 256 + t];
            sq  += bnstat[sl * 256 + 128 + t];
        }
        const float invN = 1.0f / (float)NN;
        float mean = sum * invN;
        float var  = sq * invN - mean * mean;
        float sc   = scale[t] * rsqrtf(var + 1e-5f);
        sA[t] = sc;
        bA[t] = bias[t] - mean * sc;
    }
    __syncthreads();
    int wave = t >> 6, lane = t & 63;
    int row0 = blockIdx.x * 64 + wave * 16;
    int arow = row0 + (lane & 15);
    int kb = (lane >> 4) * 8;
    bf16x8 af[4];
#pragma unroll
    for (int kt = 0; kt < 4; kt++) {
        int cb = kt * 32 + kb;
        const float* gp = G + (size_t)arow * 128 + cb;
        float4 lo = *reinterpret_cast<const float4*>(gp);
        float4 hi = *reinterpret_cast<const float4*>(gp + 4);
        bf16x8 v;
        v[0] = (short)f2bf(fmaxf(fmaf(lo.x, sA[cb + 0], bA[cb + 0]), 0.f));
        v[1] = (short)f2bf(fmaxf(fmaf(lo.y, sA[cb + 1], bA[cb + 1]), 0.f));
        v[2] = (short)f2bf(fmaxf(fmaf(lo.z, sA[cb + 2], bA[cb + 2]), 0.f));
        v[3] = (short)f2bf(fmaxf(fmaf(lo.w, sA[cb + 3], bA[cb + 3]), 0.f));
        v[4] = (short)f2bf(fmaxf(fmaf(hi.x, sA[cb + 4], bA[cb + 4]), 0.f));
        v[5] = (short)f2bf(fmaxf(fmaf(hi.y, sA[cb + 5], bA[cb + 5]), 0.f));
        v[6] = (short)f2bf(fmaxf(fmaf(hi.z, sA[cb + 6], bA[cb + 6]), 0.f));
        v[7] = (short)f2bf(fmaxf(fmaf(hi.w, sA[cb + 7], bA[cb + 7]), 0.f));
        af[kt] = v;
    }
    gemm_gat_core(af, Bf, row0, Cl, Cr, lane);
}

// policy projections: P (bf16, N x 128) = A[N,128] @ B[128,128]
__launch_bounds__(256)
__global__ void k_gemm_pol(const float* __restrict__ A, const unsigned short* __restrict__ Bf,
                           unsigned short* __restrict__ P)
{
    int wave = threadIdx.x >> 6, lane = threadIdx.x & 63;
    int row0 = blockIdx.x * 64 + wave * 16;
    bf16x8 af[4];
    load_afrag(A, row0 + (lane & 15), (lane >> 4) * 8, af);
    int crow = row0 + (lane >> 4) * 4;
    int c0 = lane & 15;
#pragma unroll
    for (int ct = 0; ct < 8; ct++) {
        f32x4 acc = {0.f, 0.f, 0.f, 0.f};
#pragma unroll
        for (int kt = 0; kt < 4; kt++) {
            bf16x8 bf = *reinterpret_cast<const bf16x8*>(Bf + ((size_t)(kt * 8 + ct) * 64 + lane) * 8);
            acc = __builtin_amdgcn_mfma_f32_16x16x32_bf16(af[kt], bf, acc, 0, 0, 0);
        }
        int col = ct * 16 + c0;
#pragma unroll
        for (int r = 0; r < 4; r++)
            P[(size_t)(crow + r) * 128 + col] = f2bf(acc[r]);
    }
}

// ---------------- GATv2 edge aggregation + fused BN stats (slotted) ----------------
// one wave per 2 consecutive dst nodes (finer grain -> better occupancy);
// no-max softmax; DPP in-row head reduction; 32B-padded attrs.

__device__ __forceinline__ float2 edge_el(uint4 A, uint2 C,
                                          const __half2 wx[6], const __half2 wy[6])
{
    __half2 e0 = *reinterpret_cast<const __half2*>(&A.x);
    __half2 e1 = *reinterpret_cast<const __half2*>(&A.y);
    __half2 e2 = *reinterpret_cast<const __half2*>(&A.z);
    __half2 e3 = *reinterpret_cast<const __half2*>(&A.w);
    __half2 e4 = *reinterpret_cast<const __half2*>(&C.x);
    __half2 e5 = *reinterpret_cast<const __half2*>(&C.y);
    __half2 ax = __hmul2(e0, wx[0]);
    ax = __hfma2(e1, wx[1], ax); ax = __hfma2(e2, wx[2], ax);
    ax = __hfma2(e3, wx[3], ax); ax = __hfma2(e4, wx[4], ax);
    ax = __hfma2(e5, wx[5], ax);
    __half2 ay = __hmul2(e0, wy[0]);
    ay = __hfma2(e1, wy[1], ay); ay = __hfma2(e2, wy[2], ay);
    ay = __hfma2(e3, wy[3], ay); ay = __hfma2(e4, wy[4], ay);
    ay = __hfma2(e5, wy[5], ay);
    float2 r;
    r.x = __half2float(__hadd(__low2half(ax), __high2half(ax)));
    r.y = __half2float(__hadd(__low2half(ay), __high2half(ay)));
    return r;
}

__launch_bounds__(256)
__global__ void k_gat(const unsigned short* __restrict__ xlb, const unsigned short* __restrict__ xrb,
                      const unsigned short* __restrict__ eaCSR,
                      const int* __restrict__ rowptr, const int* __restrict__ csr_src,
                      const float* __restrict__ We, const float* __restrict__ att,
                      const float* __restrict__ bconv, float* __restrict__ g,
                      float* __restrict__ bnstat)
{
    int wid = blockIdx.x * 4 + (threadIdx.x >> 6);   // 32768 waves, 2 nodes each
    int lane = threadIdx.x & 63;
    int f0 = lane * 2;

    const int* cs_s = (const int*)rfl64((unsigned long long)csr_src);
    const unsigned short* ea_s = (const unsigned short*)rfl64((unsigned long long)eaCSR);

    __half2 wx[6], wy[6];
#pragma unroll
    for (int j = 0; j < 6; j++) {
        float2 w0 = *reinterpret_cast<const float2*>(We + (2 * j) * 128 + f0);
        float2 w1 = *reinterpret_cast<const float2*>(We + (2 * j + 1) * 128 + f0);
        wx[j] = __floats2half2_rn(w0.x, w1.x);
        wy[j] = __floats2half2_rn(w0.y, w1.y);
    }
    float2 av = *reinterpret_cast<const float2*>(att + f0);
    av.x *= LOG2E; av.y *= LOG2E;          // base-2 logits
    float2 bc = *reinterpret_cast<const float2*>(bconv + f0);
    const char* xl_lane = reinterpret_cast<const char*>(xlb) + (lane << 2);

    float bs0 = 0.f, bs1 = 0.f, bq0 = 0.f, bq1 = 0.f;   // BN partial stats

    for (int n = wid * 2; n < wid * 2 + 2; ++n) {
        unsigned int xrw = *reinterpret_cast<const unsigned int*>(xrb + (size_t)n * 128 + f0);
        float xr0 = bflo(xrw), xr1 = bfhi(xrw);

        float sA_ = 0.f, a0A = 0.f, a1A = 0.f;
        float sB_ = 0.f, a0B = 0.f, a1B = 0.f;
        int beg = rowptr[n], end = rowptr[n + 1];
        int idx = beg;
        for (; idx + 4 <= end; idx += 4) {
            int off0 = cs_s[idx],     off1 = cs_s[idx + 1];
            int off2 = cs_s[idx + 2], off3 = cs_s[idx + 3];
            const unsigned short* ep = ea_s + (size_t)idx * 16;
            uint4 qA = *reinterpret_cast<const uint4*>(ep);
            uint2 qC = *reinterpret_cast<const uint2*>(ep + 8);
            uint4 rA = *reinterpret_cast<const uint4*>(ep + 16);
            uint2 rC = *reinterpret_cast<const uint2*>(ep + 24);
            uint4 sAq = *reinterpret_cast<const uint4*>(ep + 32);
            uint2 sC = *reinterpret_cast<const uint2*>(ep + 40);
            uint4 tA = *reinterpret_cast<const uint4*>(ep + 48);
            uint2 tC = *reinterpret_cast<const uint2*>(ep + 56);
            unsigned int xw0 = *reinterpret_cast<const unsigned int*>(xl_lane + off0);
            unsigned int xw1 = *reinterpret_cast<const unsigned int*>(xl_lane + off1);
            unsigned int xw2 = *reinterpret_cast<const unsigned int*>(xl_lane + off2);
            unsigned int xw3 = *reinterpret_cast<const unsigned int*>(xl_lane + off3);

            float2 el0 = edge_el(qA, qC, wx, wy);
            float2 el1 = edge_el(rA, rC, wx, wy);
            float2 el2 = edge_el(sAq, sC, wx, wy);
            float2 el3 = edge_el(tA, tC, wx, wy);

            float xa0 = bflo(xw0), xa1 = bfhi(xw0);
            float xb0 = bflo(xw1), xb1 = bfhi(xw1);
            float xc0 = bflo(xw2), xc1 = bfhi(xw2);
            float xd0 = bflo(xw3), xd1 = bfhi(xw3);

            float t0 = lrelu(xa0 + xr0 + el0.x) * av.x + lrelu(xa1 + xr1 + el0.y) * av.y;
            float t1 = lrelu(xb0 + xr0 + el1.x) * av.x + lrelu(xb1 + xr1 + el1.y) * av.y;
            float t2 = lrelu(xc0 + xr0 + el2.x) * av.x + lrelu(xc1 + xr1 + el2.y) * av.y;
            float t3 = lrelu(xd0 + xr0 + el3.x) * av.x + lrelu(xd1 + xr1 + el3.y) * av.y;
            t0 = head_reduce(t0); t1 = head_reduce(t1);
            t2 = head_reduce(t2); t3 = head_reduce(t3);

            float w0 = exp2f(t0);
            float w1 = exp2f(t1);
            float w2 = exp2f(t2);
            float w3 = exp2f(t3);
            sA_ += w0 + w1;
            sB_ += w2 + w3;
            a0A = fmaf(w0, xa0, fmaf(w1, xb0, a0A));
            a1A = fmaf(w0, xa1, fmaf(w1, xb1, a1A));
            a0B = fmaf(w2, xc0, fmaf(w3, xd0, a0B));
            a1B = fmaf(w2, xc1, fmaf(w3, xd1, a1B));
        }
        for (; idx < end; ++idx) {
            int off0 = cs_s[idx];
            const unsigned short* ep = ea_s + (size_t)idx * 16;
            uint4 qA = *reinterpret_cast<const uint4*>(ep);
            uint2 qC = *reinterpret_cast<const uint2*>(ep + 8);
            unsigned int xw0 = *reinterpret_cast<const unsigned int*>(xl_lane + off0);
            float2 el0 = edge_el(qA, qC, wx, wy);
            float xa0 = bflo(xw0), xa1 = bfhi(xw0);
            float tt = lrelu(xa0 + xr0 + el0.x) * av.x + lrelu(xa1 + xr1 + el0.y) * av.y;
            tt = head_reduce(tt);
            float w = exp2f(tt);
            sA_ += w;
            a0A = fmaf(w, xa0, a0A);
            a1A = fmaf(w, xa1, a1A);
        }
        float s  = sA_ + sB_;
        float a0 = a0A + a0B;
        float a1 = a1A + a1B;
        float inv = 1.f / s;   // s > 0 guaranteed by the self-loop
        float r0 = fmaf(a0, inv, bc.x);
        float r1 = fmaf(a1, inv, bc.y);
        *reinterpret_cast<float2*>(g + (size_t)n * 128 + f0) = make_float2(r0, r1);
        bs0 += r0; bs1 += r1;
        bq0 = fmaf(r0, r0, bq0); bq1 = fmaf(r1, r1, bq1);
    }

    // block-level BN stat reduction into slot (blockIdx & 63): 8192 blocks -> chain 128
    __shared__ float red[256 * 4];
    int t = threadIdx.x;
    red[t * 4 + 0] = bs0; red[t * 4 + 1] = bs1;
    red[t * 4 + 2] = bq0; red[t * 4 + 3] = bq1;
    __syncthreads();
    if (t < 64) {
        float v0 = red[t * 4 + 0] + red[(t + 64) * 4 + 0] + red[(t + 128) * 4 + 0] + red[(t + 192) * 4 + 0];
        float v1 = red[t * 4 + 1] + red[(t + 64) * 4 + 1] + red[(t + 128) * 4 + 1] + red[(t + 192) * 4 + 1];
        float q0 = red[t * 4 + 2] + red[(t + 64) * 4 + 2] + red[(t + 128) * 4 + 2] + red[(t + 192) * 4 + 2];
        float q1 = red[t * 4 + 3] + red[(t + 64) * 4 + 3] + red[(t + 128) * 4 + 3] + red[(t + 192) * 4 + 3];
        float* slot = bnstat + (size_t)(blockIdx.x & (NSLOT - 1)) * 256;
        atomicAdd(&slot[2 * t + 0], v0);
        atomicAdd(&slot[2 * t + 1], v1);
        atomicAdd(&slot[128 + 2 * t + 0], q0);
        atomicAdd(&slot[128 + 2 * t + 1], q1);
    }
}

// ---------------- BN apply (odd layers only: + residual + relu) ----------------

__launch_bounds__(256)
__global__ void k_bnapply_res_relu(const float4* __restrict__ gin,
                                   const float* __restrict__ bnstat,
                                   const float* __restrict__ scale, const float* __restrict__ bias,
                                   float4* __restrict__ hbuf)
{
    __shared__ float sA[128], bA[128];
    int t = threadIdx.x;
    if (t < 128) {
        float sum = 0.f, sq = 0.f;
#pragma unroll
        for (int sl = 0; sl < NSLOT; sl++) {
            sum += bnstat[sl * 256 + t];
            sq  += bnstat[sl * 256 + 128 + t];
        }
        const float invN = 1.0f / (float)NN;
        float mean = sum * invN;
        float var  = sq * invN - mean * mean;
        float sc   = scale[t] * rsqrtf(var + 1e-5f);
        sA[t] = sc;
        bA[t] = bias[t] - mean * sc;
    }
    __syncthreads();
    int idx = blockIdx.x * 256 + t;
    int c4 = (idx & 31) * 4;
    float4 v = gin[idx];
    float4 hv = hbuf[idx];
    float4 r;
    r.x = fmaxf(fmaf(v.x, sA[c4 + 0], bA[c4 + 0]) + hv.x, 0.f);
    r.y = fmaxf(fmaf(v.y, sA[c4 + 1], bA[c4 + 1]) + hv.y, 0.f);
    r.z = fmaxf(fmaf(v.z, sA[c4 + 2], bA[c4 + 2]) + hv.z, 0.f);
    r.w = fmaxf(fmaf(v.w, sA[c4 + 3], bA[c4 + 3]) + hv.w, 0.f);
    hbuf[idx] = r;
}

// ---------------- pooling + value head ----------------

__launch_bounds__(128)
__global__ void k_pool(const float* __restrict__ h, const int* __restrict__ batch,
                       float* __restrict__ pooled, float* __restrict__ cnt)
{
    int c = threadIdx.x;
    int r0 = blockIdx.x * 128;
    int cur = batch[r0];
    float acc = 0.f;
    float run = 0.f;
    for (int i = 0; i < 128; ++i) {
        int r = r0 + i;
        int b = batch[r];
        if (b != cur) {
            atomicAdd(&pooled[(size_t)cur * 128 + c], acc);
            if (c == 0) atomicAdd(&cnt[cur], run);
            acc = 0.f; run = 0.f; cur = b;
        }
        acc += h[(size_t)r * 128 + c];
        run += 1.f;
    }
    atomicAdd(&pooled[(size_t)cur * 128 + c], acc);
    if (c == 0) atomicAdd(&cnt[cur], run);
}

__launch_bounds__(64)
__global__ void k_value(const float* __restrict__ pooled, const float* __restrict__ cnt,
                        const float* __restrict__ Wv1, const float* __restrict__ bv1,
                        const float* __restrict__ Wv2, const float* __restrict__ bv2,
                        float* __restrict__ out)
{
    int gi = blockIdx.x;
    int l = threadIdx.x;
    float inv = 1.f / fmaxf(cnt[gi], 1.f);
    const float* pr = pooled + (size_t)gi * 128;
    float z = bv1[l];
    for (int k = 0; k < 128; k++) z = fmaf(pr[k] * inv, Wv1[k * 64 + l], z);
    z = fmaxf(z, 0.f);
#pragma unroll
    for (int j = 0; j < 3; j++) {
        float p = z * Wv2[l * 3 + j];
        p += __shfl_xor(p, 32); p += __shfl_xor(p, 16); p += __shfl_xor(p, 8);
        p += __shfl_xor(p, 4);  p += __shfl_xor(p, 2);  p += __shfl_xor(p, 1);
        if (l == 0) out[gi * 3 + j] = p + bv2[j];
    }
}

// ---------------- policy head in CSR order ----------------
// P2[dst] reads are sequential (dst sorted); attrs from f16 eaCSR (sequential);
// only P1[src] is a gather. Output scattered by csr_eid (-1 = self-loop, skipped).

__device__ __forceinline__ void dec12(uint4 A, uint2 C, float* o)
{
    __half2 h;
    h = *reinterpret_cast<__half2*>(&A.x); o[0] = __low2float(h); o[1]  = __high2float(h);
    h = *reinterpret_cast<__half2*>(&A.y); o[2] = __low2float(h); o[3]  = __high2float(h);
    h = *reinterpret_cast<__half2*>(&A.z); o[4] = __low2float(h); o[5]  = __high2float(h);
    h = *reinterpret_cast<__half2*>(&A.w); o[6] = __low2float(h); o[7]  = __high2float(h);
    h = *reinterpret_cast<__half2*>(&C.x); o[8] = __low2float(h); o[9]  = __high2float(h);
    h = *reinterpret_cast<__half2*>(&C.y); o[10] = __low2float(h); o[11] = __high2float(h);
}

__launch_bounds__(256)
__global__ void k_policy(const unsigned short* __restrict__ P,
                         const unsigned short* __restrict__ eaCSR,
                         const int* __restrict__ csr_src, const int* __restrict__ csr_dst,
                         const int* __restrict__ csr_eid,
                         const float* __restrict__ Wp1c, const float* __restrict__ bp1,
                         const float* __restrict__ Wp2, const float* __restrict__ bp2,
                         float* __restrict__ out)
{
    int wave = (blockIdx.x * 256 + threadIdx.x) >> 6;   // 73728 waves, 8 CSR positions each
    int lane = threadIdx.x & 63;
    const unsigned short* ea_s = (const unsigned short*)rfl64((unsigned long long)eaCSR);
    const int* cs_s = (const int*)rfl64((unsigned long long)csr_src);
    const int* cd_s = (const int*)rfl64((unsigned long long)csr_dst);
    const int* ce_s = (const int*)rfl64((unsigned long long)csr_eid);
    const char* Pb = reinterpret_cast<const char*>(P);
    float w1c[12];
#pragma unroll
    for (int k = 0; k < 12; k++) w1c[k] = Wp1c[k * 64 + lane];
    float wp2 = Wp2[lane];
    float bb = bp1[lane];
    float b2 = bp2[0];
    int lb = lane * 2;
    for (int i = 0; i < 8; i += 2) {
        int p0 = wave * 8 + i;
        int p1 = p0 + 1;
        int e0 = ce_s[p0], e1 = ce_s[p1];
        int so0 = cs_s[p0], so1 = cs_s[p1];
        int do0 = cd_s[p0], do1 = cd_s[p1];
        const unsigned short* a0p = ea_s + (size_t)p0 * 16;
        uint4 A0 = *reinterpret_cast<const uint4*>(a0p);
        uint2 C0 = *reinterpret_cast<const uint2*>(a0p + 8);
        uint4 A1 = *reinterpret_cast<const uint4*>(a0p + 16);
        uint2 C1 = *reinterpret_cast<const uint2*>(a0p + 24);
        unsigned short ps0 = *reinterpret_cast<const unsigned short*>(Pb + so0 + lb);
        unsigned short pd0 = *reinterpret_cast<const unsigned short*>(Pb + do0 + 128 + lb);
        unsigned short ps1 = *reinterpret_cast<const unsigned short*>(Pb + so1 + lb);
        unsigned short pd1 = *reinterpret_cast<const unsigned short*>(Pb + do1 + 128 + lb);

        float ea0[12], ea1[12];
        dec12(A0, C0, ea0);
        dec12(A1, C1, ea1);

        float z0 = bf2f(ps0) + bf2f(pd0) + bb;
        float z1 = bf2f(ps1) + bf2f(pd1) + bb;
#pragma unroll
        for (int k = 0; k < 12; k++) {
            z0 = fmaf(ea0[k], w1c[k], z0);
            z1 = fmaf(ea1[k], w1c[k], z1);
        }
        float p0v = fmaxf(z0, 0.f) * wp2;
        float p1v = fmaxf(z1, 0.f) * wp2;
        p0v = head_reduce(p0v);
        p1v = head_reduce(p1v);
        p0v += __shfl_xor(p0v, 16); p1v += __shfl_xor(p1v, 16);
        p0v += __shfl_xor(p0v, 32); p1v += __shfl_xor(p1v, 32);
        if (lane == 0) {
            if (e0 >= 0) out[3072 + e0] = p0v + b2;
            if (e1 >= 0) out[3072 + e1] = p1v + b2;
        }
    }
}

// ---------------- host ----------------

extern "C" void kernel_launch(void* const* d_in, const int* in_sizes, int n_in,
                              void* d_out, int out_size, void* d_ws, size_t ws_size,
                              hipStream_t stream)
{
    const float* x     = (const float*)d_in[0];
    const float* eattr = (const float*)d_in[1];
    const int*   eidx  = (const int*)d_in[2];
    const int*   batch = (const int*)d_in[3];
    const float* Win   = (const float*)d_in[4];
    const float* bin   = (const float*)d_in[5];
    const float* Wl    = (const float*)d_in[6];
    const float* Wr    = (const float*)d_in[7];
    const float* We    = (const float*)d_in[8];
    const float* att   = (const float*)d_in[9];
    const float* bconv = (const float*)d_in[10];
    const float* bnsc  = (const float*)d_in[11];
    const float* bnbi  = (const float*)d_in[12];
    const float* Wv1   = (const float*)d_in[13];
    const float* bv1   = (const float*)d_in[14];
    const float* Wv2   = (const float*)d_in[15];
    const float* bv2   = (const float*)d_in[16];
    const float* Wp1   = (const float*)d_in[17];
    const float* bp1   = (const float*)d_in[18];
    const float* Wp2   = (const float*)d_in[19];
    const float* bp2   = (const float*)d_in[20];
    float* out = (float*)d_out;

    const int* src0 = eidx;
    const int* dst0 = eidx + EE;

    const size_t NH = (size_t)NN * 128;
    float* ws = (float*)d_ws;
    float* h  = ws;                    // N*128 fp32
    float* g  = h + NH;                // N*128 fp32
    unsigned short* xlb = (unsigned short*)(g + NH);        // N*128 bf16 (reused as policy P)
    unsigned short* xrb = xlb + NH;                          // N*128 bf16
    unsigned short* eaCSR = xrb + NH;                        // EPX*16 f16 (32B/edge, padded)
    int* rowptr = (int*)(eaCSR + (size_t)EPX * 16);          // N+1
    int* csr_src = rowptr + (NN + 1);                        // EPX (byte offsets)
    int* csr_dst = csr_src + EPX;                            // EPX (byte offsets)
    int* csr_eid = csr_dst + EPX;                            // EPX (edge ids, -1 = self)
    // --- zeroed region (one memset) ---
    int* deg  = csr_eid + EPX;         // N
    int* fill = deg + NN;              // N
    float* bnstat = (float*)(fill + NN);        // 8 layers * NSLOT * 256
    float* pooled = bnstat + 8 * NSLOT * 256;   // G*128
    float* cnt    = pooled + (size_t)GG * 128;  // G
    size_t zero_elems = (size_t)NN + NN + 8 * NSLOT * 256 + (size_t)GG * 128 + GG;
    // --- MFMA-swizzled weights (fully rewritten each launch) ---
    unsigned short* wg = (unsigned short*)(cnt + GG);   // 8*32768
    unsigned short* wp = wg + 8 * 32768;                // 16384

    hipMemsetAsync(deg, 0, zero_elems * sizeof(float), stream);

    // CSR build + weight prep
    k_deg<<<EE / 256, 256, 0, stream>>>(dst0, deg);
    k_scan<<<1, 1024, 0, stream>>>(deg, rowptr);
    k_scatter<<<EPX / 256, 256, 0, stream>>>(src0, dst0, eattr, rowptr, deg, fill,
                                             csr_src, csr_dst, csr_eid, eaCSR);
    k_selfattr<<<(NN * 16) / 256, 256, 0, stream>>>(rowptr, eaCSR);
    k_wprep<<<136, 256, 0, stream>>>(Wl, Wr, Wp1, wg, wp);

    // input layer
    k_input<<<NN / 16, 256, 0, stream>>>(x, Win, bin, h);

    // 8 GATv2 + BN layers (even: g->stats; odd: BN fused into GEMM A-load, then res+relu)
    for (int l = 0; l < 8; l++) {
        float* bs = bnstat + (size_t)l * NSLOT * 256;
        if (l % 2 == 0) {
            k_gemm_gat<<<NN / 64, 256, 0, stream>>>(h, wg + (size_t)l * 32768, xlb, xrb);
        } else {
            float* bsp = bnstat + (size_t)(l - 1) * NSLOT * 256;   // previous layer's stats
            k_gemm_gat_bn<<<NN / 64, 256, 0, stream>>>(g, bsp,
                                                       bnsc + (size_t)(l - 1) * 128,
                                                       bnbi + (size_t)(l - 1) * 128,
                                                       wg + (size_t)l * 32768, xlb, xrb);
        }
        k_gat<<<NN / 8, 256, 0, stream>>>(xlb, xrb, eaCSR, rowptr, csr_src,
                                          We + (size_t)l * 1536, att + (size_t)l * 128,
                                          bconv + (size_t)l * 128, g, bs);
        if (l % 2 == 1) {
            k_bnapply_res_relu<<<(NN * 128 / 4) / 256, 256, 0, stream>>>(
                (const float4*)g, bs, bnsc + (size_t)l * 128, bnbi + (size_t)l * 128,
                (float4*)h);
        }
    }

    // pooling + value head
    k_pool<<<NN / 128, 128, 0, stream>>>(h, batch, pooled, cnt);
    k_value<<<GG, 64, 0, stream>>>(pooled, cnt, Wv1, bv1, Wv2, bv2, out);

    // policy head (P stored bf16 in xlb; CSR-ordered traversal)
    unsigned short* P = xlb;
    k_gemm_pol<<<NN / 64, 256, 0, stream>>>(h, wp, P);
    k_policy<<<(EPX / 8) / 4, 256, 0, stream>>>(P, eaCSR, csr_src, csr_dst, csr_eid,
                                                Wp1 + 256 * 64, bp1, Wp2, bp2, out);
}

// Round 15
// 1081.520 us; speedup vs baseline: 1.0809x; 1.0809x over previous
//
#include <hip/hip_runtime.h>
#include <hip/hip_fp16.h>

#define NN 65536
#define EE 524288
#define EPX 589824   // EE + NN
#define GG 1024
#define NSLOT 32     // BN stat slot copies (breaks atomic contention)

typedef __attribute__((ext_vector_type(8))) short bf16x8;
typedef __attribute__((ext_vector_type(4))) float f32x4;

#define LOG2E 1.44269504088896f

// ---------------- bf16/f16 helpers ----------------

__device__ __forceinline__ unsigned short f2bf(float x) {
    unsigned int u = __float_as_uint(x);
    u += 0x7FFFu + ((u >> 16) & 1u);      // round-to-nearest-even
    return (unsigned short)(u >> 16);
}
__device__ __forceinline__ float bflo(unsigned int w) { return __uint_as_float(w << 16); }
__device__ __forceinline__ float bfhi(unsigned int w) { return __uint_as_float(w & 0xFFFF0000u); }
__device__ __forceinline__ float bf2f(unsigned short u) { return __uint_as_float((unsigned int)u << 16); }
__device__ __forceinline__ float lrelu(float x) { return fmaf(0.4f, fabsf(x), 0.6f * x); }
__device__ __forceinline__ unsigned int packh2(float a, float b) {
    __half2 h = __floats2half2_rn(a, b);
    return *reinterpret_cast<unsigned int*>(&h);
}
__device__ __forceinline__ unsigned long long rfl64(unsigned long long v) {
    unsigned int lo = __builtin_amdgcn_readfirstlane((unsigned int)v);
    unsigned int hi = __builtin_amdgcn_readfirstlane((unsigned int)(v >> 32));
    return (((unsigned long long)hi) << 32) | lo;
}

// DPP-based in-row reduce: sum over each 16-lane row, result in all 16 lanes. Pure VALU.
template <int CTRL>
__device__ __forceinline__ float dpp_add(float v) {
    int x = __builtin_amdgcn_update_dpp(0, __float_as_int(v), CTRL, 0xf, 0xf, true);
    return v + __int_as_float(x);
}
__device__ __forceinline__ float head_reduce(float t) {
    t = dpp_add<0xB1>(t);    // quad_perm [1,0,3,2]  (xor 1)
    t = dpp_add<0x4E>(t);    // quad_perm [2,3,0,1]  (xor 2)
    t = dpp_add<0x124>(t);   // row_ror:4
    t = dpp_add<0x128>(t);   // row_ror:8  -> full 16-lane sum
    return t;
}

// ---------------- CSR build ----------------

__launch_bounds__(256)
__global__ void k_deg(const int* __restrict__ dst0, int* __restrict__ deg)
{
    int e = blockIdx.x * 256 + threadIdx.x;
    if (e >= EE) return;
    atomicAdd(&deg[dst0[e]], 1);
}

__launch_bounds__(1024)
__global__ void k_scan(const int* __restrict__ deg, int* __restrict__ rowptr)
{
    __shared__ int sums[1024];
    int t = threadIdx.x;
    int base = t * 64;
    int s = 0;
    for (int i = 0; i < 64; i++) s += deg[base + i] + 1;
    sums[t] = s;
    __syncthreads();
    for (int off = 1; off < 1024; off <<= 1) {
        int v = (t >= off) ? sums[t - off] : 0;
        __syncthreads();
        sums[t] += v;
        __syncthreads();
    }
    int off = sums[t] - s;   // exclusive prefix
    for (int i = 0; i < 64; i++) { rowptr[base + i] = off; off += deg[base + i] + 1; }
    if (t == 1023) rowptr[NN] = off;
}

// scatter edges into CSR order; attrs -> f16 padded 32B/edge in CSR order AND in
// original edge order (eaOrd, for the policy head). csr_src holds BYTE offsets.
__launch_bounds__(256)
__global__ void k_scatter(const int* __restrict__ src0, const int* __restrict__ dst0,
                          const float* __restrict__ eattr,
                          const int* __restrict__ rowptr, const int* __restrict__ deg,
                          int* __restrict__ fill, int* __restrict__ csr_src,
                          unsigned short* __restrict__ eaCSR,
                          unsigned short* __restrict__ eaOrd)
{
    int e = blockIdx.x * 256 + threadIdx.x;
    if (e >= EPX) return;
    if (e < EE) {
        int d = dst0[e];
        int pos = rowptr[d] + atomicAdd(&fill[d], 1);
        csr_src[pos] = src0[e] << 8;   // byte offset into bf16 row (128*2B)
        const float* ep = eattr + (size_t)e * 12;
        float4 a = *reinterpret_cast<const float4*>(ep);
        float4 b = *reinterpret_cast<const float4*>(ep + 4);
        float4 c = *reinterpret_cast<const float4*>(ep + 8);
        uint4 w; w.x = packh2(a.x, a.y); w.y = packh2(a.z, a.w);
        w.z = packh2(b.x, b.y); w.w = packh2(b.z, b.w);
        uint2 w2 = make_uint2(packh2(c.x, c.y), packh2(c.z, c.w));
        unsigned short* o = eaCSR + (size_t)pos * 16;
        *reinterpret_cast<uint4*>(o) = w;
        *reinterpret_cast<uint2*>(o + 8) = w2;
        unsigned short* o2 = eaOrd + (size_t)e * 16;
        *reinterpret_cast<uint4*>(o2) = w;
        *reinterpret_cast<uint2*>(o2 + 8) = w2;
    } else {
        int n = e - EE;
        csr_src[rowptr[n] + deg[n]] = n << 8;   // self-loop in the last slot
    }
}

// fill each node's self-loop attr slot with the mean of its real incoming edge attrs.
__launch_bounds__(256)
__global__ void k_selfattr(const int* __restrict__ rowptr, unsigned short* __restrict__ eaCSR)
{
    int tid = blockIdx.x * 256 + threadIdx.x;   // NN*16 threads
    int n = tid >> 4;
    int lk = tid & 15;
    if (lk >= 12) return;
    int beg = rowptr[n], endm1 = rowptr[n + 1] - 1;
    float s = 0.f;
    for (int p = beg; p < endm1; ++p) {
        __half h = *reinterpret_cast<const __half*>(&eaCSR[(size_t)p * 16 + lk]);
        s += __half2float(h);
    }
    float dv = fmaxf((float)(endm1 - beg), 1.0f);
    __half ho = __float2half(s / dv);
    eaCSR[(size_t)endm1 * 16 + lk] = *reinterpret_cast<unsigned short*>(&ho);
}

// ---------------- MFMA weight prep: swizzle W into 16x16x32 B-fragment order ----------------

__launch_bounds__(256)
__global__ void k_wprep(const float* __restrict__ Wl, const float* __restrict__ Wr,
                        const float* __restrict__ Wp1,
                        unsigned short* __restrict__ wg, unsigned short* __restrict__ wp)
{
    int tid = blockIdx.x * 256 + threadIdx.x;   // 34816 threads
    if (tid < 32768) {
        int l = tid >> 12;
        int r = tid & 4095;
        int kt = r >> 10, ct = (r >> 6) & 15, lane = r & 63;
        int kb = kt * 32 + (lane >> 4) * 8;
        int col = ct * 16 + (lane & 15);
        const float* W = (col < 128) ? (Wl + (size_t)l * 16384 + col)
                                     : (Wr + (size_t)l * 16384 + (col - 128));
        unsigned short* o = wg + (size_t)tid * 8;
#pragma unroll
        for (int j = 0; j < 8; j++) o[j] = f2bf(W[(size_t)(kb + j) * 128]);
    } else if (tid < 34816) {
        int r = tid - 32768;
        int kt = r >> 9, ct = (r >> 6) & 7, lane = r & 63;
        int kb = kt * 32 + (lane >> 4) * 8;
        int col = ct * 16 + (lane & 15);
        const float* W = (col < 64) ? (Wp1 + col) : (Wp1 + 128 * 64 + (col - 64));
        unsigned short* o = wp + (size_t)r * 8;
#pragma unroll
        for (int j = 0; j < 8; j++) o[j] = f2bf(W[(size_t)(kb + j) * 64]);
    }
}

// ---------------- input layer: h = relu(x @ Win + bin) ----------------

__launch_bounds__(256)
__global__ void k_input(const float* __restrict__ x, const float* __restrict__ Win,
                        const float* __restrict__ bin, float* __restrict__ h)
{
    __shared__ float W[21 * 128];
    int t = threadIdx.x;
    for (int i = t; i < 21 * 128; i += 256) W[i] = Win[i];
    __syncthreads();
    int c = t & 127, sub = t >> 7;
    int n0 = blockIdx.x * 16;
    float bc = bin[c];
    for (int i = 0; i < 8; i++) {
        int n = n0 + sub + i * 2;
        const float* xp = x + (size_t)n * 21;
        float acc = bc;
#pragma unroll
        for (int k = 0; k < 21; k++) acc = fmaf(xp[k], W[k * 128 + c], acc);
        h[(size_t)n * 128 + c] = fmaxf(acc, 0.f);
    }
}

// ---------------- MFMA GEMMs (no LDS; A fp32 -> bf16 in-register; B pre-swizzled) ----------------

__device__ __forceinline__ void load_afrag(const float* __restrict__ A, int arow, int kb,
                                           bf16x8 af[4])
{
#pragma unroll
    for (int kt = 0; kt < 4; kt++) {
        const float* ap = A + (size_t)arow * 128 + kt * 32 + kb;
        float4 lo = *reinterpret_cast<const float4*>(ap);
        float4 hi = *reinterpret_cast<const float4*>(ap + 4);
        bf16x8 v;
        v[0] = (short)f2bf(lo.x); v[1] = (short)f2bf(lo.y);
        v[2] = (short)f2bf(lo.z); v[3] = (short)f2bf(lo.w);
        v[4] = (short)f2bf(hi.x); v[5] = (short)f2bf(hi.y);
        v[6] = (short)f2bf(hi.z); v[7] = (short)f2bf(hi.w);
        af[kt] = v;
    }
}

__device__ __forceinline__ void gemm_gat_core(const bf16x8 af[4], const unsigned short* __restrict__ Bf,
                                              int row0, unsigned short* __restrict__ Cl,
                                              unsigned short* __restrict__ Cr, int lane)
{
    int crow = row0 + (lane >> 4) * 4;
    int c0 = lane & 15;
#pragma unroll
    for (int ct = 0; ct < 16; ct++) {
        f32x4 acc = {0.f, 0.f, 0.f, 0.f};
#pragma unroll
        for (int kt = 0; kt < 4; kt++) {
            bf16x8 bf = *reinterpret_cast<const bf16x8*>(Bf + ((size_t)(kt * 16 + ct) * 64 + lane) * 8);
            acc = __builtin_amdgcn_mfma_f32_16x16x32_bf16(af[kt], bf, acc, 0, 0, 0);
        }
        int col = ct * 16 + c0;
        unsigned short* C = (col < 128) ? Cl : Cr;
        int cc = col & 127;
#pragma unroll
        for (int r = 0; r < 4; r++)
            C[(size_t)(crow + r) * 128 + cc] = f2bf(acc[r]);
    }
}

// xl|xr = h @ [Wl|Wr], plain fp32 A
__launch_bounds__(256)
__global__ void k_gemm_gat(const float* __restrict__ A, const unsigned short* __restrict__ Bf,
                           unsigned short* __restrict__ Cl, unsigned short* __restrict__ Cr)
{
    int wave = threadIdx.x >> 6, lane = threadIdx.x & 63;
    int row0 = blockIdx.x * 64 + wave * 16;
    bf16x8 af[4];
    load_afrag(A, row0 + (lane & 15), (lane >> 4) * 8, af);
    gemm_gat_core(af, Bf, row0, Cl, Cr, lane);
}

// xl|xr = relu(bn(g)) @ [Wl|Wr]: BN coeffs from slotted stats, applied on the A-load.
__launch_bounds__(256)
__global__ void k_gemm_gat_bn(const float* __restrict__ G, const float* __restrict__ bnstat,
                              const float* __restrict__ scale, const float* __restrict__ bias,
                              const unsigned short* __restrict__ Bf,
                              unsigned short* __restrict__ Cl, unsigned short* __restrict__ Cr)
{
    __shared__ float sA[128], bA[128];
    int t = threadIdx.x;
    if (t < 128) {
        float sum = 0.f, sq = 0.f;
#pragma unroll
        for (int sl = 0; sl < NSLOT; sl++) {
            sum += bnstat[sl * 256 + t];
            sq  += bnstat[sl * 256 + 128 + t];
        }
        const float invN = 1.0f / (float)NN;
        float mean = sum * invN;
        float var  = sq * invN - mean * mean;
        float sc   = scale[t] * rsqrtf(var + 1e-5f);
        sA[t] = sc;
        bA[t] = bias[t] - mean * sc;
    }
    __syncthreads();
    int wave = t >> 6, lane = t & 63;
    int row0 = blockIdx.x * 64 + wave * 16;
    int arow = row0 + (lane & 15);
    int kb = (lane >> 4) * 8;
    bf16x8 af[4];
#pragma unroll
    for (int kt = 0; kt < 4; kt++) {
        int cb = kt * 32 + kb;
        const float* gp = G + (size_t)arow * 128 + cb;
        float4 lo = *reinterpret_cast<const float4*>(gp);
        float4 hi = *reinterpret_cast<const float4*>(gp + 4);
        bf16x8 v;
        v[0] = (short)f2bf(fmaxf(fmaf(lo.x, sA[cb + 0], bA[cb + 0]), 0.f));
        v[1] = (short)f2bf(fmaxf(fmaf(lo.y, sA[cb + 1], bA[cb + 1]), 0.f));
        v[2] = (short)f2bf(fmaxf(fmaf(lo.z, sA[cb + 2], bA[cb + 2]), 0.f));
        v[3] = (short)f2bf(fmaxf(fmaf(lo.w, sA[cb + 3], bA[cb + 3]), 0.f));
        v[4] = (short)f2bf(fmaxf(fmaf(hi.x, sA[cb + 4], bA[cb + 4]), 0.f));
        v[5] = (short)f2bf(fmaxf(fmaf(hi.y, sA[cb + 5], bA[cb + 5]), 0.f));
        v[6] = (short)f2bf(fmaxf(fmaf(hi.z, sA[cb + 6], bA[cb + 6]), 0.f));
        v[7] = (short)f2bf(fmaxf(fmaf(hi.w, sA[cb + 7], bA[cb + 7]), 0.f));
        af[kt] = v;
    }
    gemm_gat_core(af, Bf, row0, Cl, Cr, lane);
}

// policy projections: P (bf16, N x 128) = A[N,128] @ B[128,128]
__launch_bounds__(256)
__global__ void k_gemm_pol(const float* __restrict__ A, const unsigned short* __restrict__ Bf,
                           unsigned short* __restrict__ P)
{
    int wave = threadIdx.x >> 6, lane = threadIdx.x & 63;
    int row0 = blockIdx.x * 64 + wave * 16;
    bf16x8 af[4];
    load_afrag(A, row0 + (lane & 15), (lane >> 4) * 8, af);
    int crow = row0 + (lane >> 4) * 4;
    int c0 = lane & 15;
#pragma unroll
    for (int ct = 0; ct < 8; ct++) {
        f32x4 acc = {0.f, 0.f, 0.f, 0.f};
#pragma unroll
        for (int kt = 0; kt < 4; kt++) {
            bf16x8 bf = *reinterpret_cast<const bf16x8*>(Bf + ((size_t)(kt * 8 + ct) * 64 + lane) * 8);
            acc = __builtin_amdgcn_mfma_f32_16x16x32_bf16(af[kt], bf, acc, 0, 0, 0);
        }
        int col = ct * 16 + c0;
#pragma unroll
        for (int r = 0; r < 4; r++)
            P[(size_t)(crow + r) * 128 + col] = f2bf(acc[r]);
    }
}

// ---------------- GATv2 edge aggregation + fused BN stats (slotted) ----------------
// one wave per 4 consecutive dst nodes; no-max softmax; DPP head reduce; 32B attrs.

__device__ __forceinline__ float2 edge_el(uint4 A, uint2 C,
                                          const __half2 wx[6], const __half2 wy[6])
{
    __half2 e0 = *reinterpret_cast<const __half2*>(&A.x);
    __half2 e1 = *reinterpret_cast<const __half2*>(&A.y);
    __half2 e2 = *reinterpret_cast<const __half2*>(&A.z);
    __half2 e3 = *reinterpret_cast<const __half2*>(&A.w);
    __half2 e4 = *reinterpret_cast<const __half2*>(&C.x);
    __half2 e5 = *reinterpret_cast<const __half2*>(&C.y);
    __half2 ax = __hmul2(e0, wx[0]);
    ax = __hfma2(e1, wx[1], ax); ax = __hfma2(e2, wx[2], ax);
    ax = __hfma2(e3, wx[3], ax); ax = __hfma2(e4, wx[4], ax);
    ax = __hfma2(e5, wx[5], ax);
    __half2 ay = __hmul2(e0, wy[0]);
    ay = __hfma2(e1, wy[1], ay); ay = __hfma2(e2, wy[2], ay);
    ay = __hfma2(e3, wy[3], ay); ay = __hfma2(e4, wy[4], ay);
    ay = __hfma2(e5, wy[5], ay);
    float2 r;
    r.x = __half2float(__hadd(__low2half(ax), __high2half(ax)));
    r.y = __half2float(__hadd(__low2half(ay), __high2half(ay)));
    return r;
}

__launch_bounds__(256)
__global__ void k_gat(const unsigned short* __restrict__ xlb, const unsigned short* __restrict__ xrb,
                      const unsigned short* __restrict__ eaCSR,
                      const int* __restrict__ rowptr, const int* __restrict__ csr_src,
                      const float* __restrict__ We, const float* __restrict__ att,
                      const float* __restrict__ bconv, float* __restrict__ g,
                      float* __restrict__ bnstat)
{
    int wid = blockIdx.x * 4 + (threadIdx.x >> 6);   // 16384 waves, 4 nodes each
    int lane = threadIdx.x & 63;
    int f0 = lane * 2;

    const int* cs_s = (const int*)rfl64((unsigned long long)csr_src);
    const unsigned short* ea_s = (const unsigned short*)rfl64((unsigned long long)eaCSR);

    __half2 wx[6], wy[6];
#pragma unroll
    for (int j = 0; j < 6; j++) {
        float2 w0 = *reinterpret_cast<const float2*>(We + (2 * j) * 128 + f0);
        float2 w1 = *reinterpret_cast<const float2*>(We + (2 * j + 1) * 128 + f0);
        wx[j] = __floats2half2_rn(w0.x, w1.x);
        wy[j] = __floats2half2_rn(w0.y, w1.y);
    }
    float2 av = *reinterpret_cast<const float2*>(att + f0);
    av.x *= LOG2E; av.y *= LOG2E;          // base-2 logits
    float2 bc = *reinterpret_cast<const float2*>(bconv + f0);
    const char* xl_lane = reinterpret_cast<const char*>(xlb) + (lane << 2);

    float bs0 = 0.f, bs1 = 0.f, bq0 = 0.f, bq1 = 0.f;   // BN partial stats

    for (int n = wid * 4; n < wid * 4 + 4; ++n) {
        unsigned int xrw = *reinterpret_cast<const unsigned int*>(xrb + (size_t)n * 128 + f0);
        float xr0 = bflo(xrw), xr1 = bfhi(xrw);

        float sA_ = 0.f, a0A = 0.f, a1A = 0.f;
        float sB_ = 0.f, a0B = 0.f, a1B = 0.f;
        int beg = rowptr[n], end = rowptr[n + 1];
        int idx = beg;
        for (; idx + 4 <= end; idx += 4) {
            int off0 = cs_s[idx],     off1 = cs_s[idx + 1];
            int off2 = cs_s[idx + 2], off3 = cs_s[idx + 3];
            const unsigned short* ep = ea_s + (size_t)idx * 16;
            uint4 qA = *reinterpret_cast<const uint4*>(ep);
            uint2 qC = *reinterpret_cast<const uint2*>(ep + 8);
            uint4 rA = *reinterpret_cast<const uint4*>(ep + 16);
            uint2 rC = *reinterpret_cast<const uint2*>(ep + 24);
            uint4 sAq = *reinterpret_cast<const uint4*>(ep + 32);
            uint2 sC = *reinterpret_cast<const uint2*>(ep + 40);
            uint4 tA = *reinterpret_cast<const uint4*>(ep + 48);
            uint2 tC = *reinterpret_cast<const uint2*>(ep + 56);
            unsigned int xw0 = *reinterpret_cast<const unsigned int*>(xl_lane + off0);
            unsigned int xw1 = *reinterpret_cast<const unsigned int*>(xl_lane + off1);
            unsigned int xw2 = *reinterpret_cast<const unsigned int*>(xl_lane + off2);
            unsigned int xw3 = *reinterpret_cast<const unsigned int*>(xl_lane + off3);

            float2 el0 = edge_el(qA, qC, wx, wy);
            float2 el1 = edge_el(rA, rC, wx, wy);
            float2 el2 = edge_el(sAq, sC, wx, wy);
            float2 el3 = edge_el(tA, tC, wx, wy);

            float xa0 = bflo(xw0), xa1 = bfhi(xw0);
            float xb0 = bflo(xw1), xb1 = bfhi(xw1);
            float xc0 = bflo(xw2), xc1 = bfhi(xw2);
            float xd0 = bflo(xw3), xd1 = bfhi(xw3);

            float t0 = lrelu(xa0 + xr0 + el0.x) * av.x + lrelu(xa1 + xr1 + el0.y) * av.y;
            float t1 = lrelu(xb0 + xr0 + el1.x) * av.x + lrelu(xb1 + xr1 + el1.y) * av.y;
            float t2 = lrelu(xc0 + xr0 + el2.x) * av.x + lrelu(xc1 + xr1 + el2.y) * av.y;
            float t3 = lrelu(xd0 + xr0 + el3.x) * av.x + lrelu(xd1 + xr1 + el3.y) * av.y;
            t0 = head_reduce(t0); t1 = head_reduce(t1);
            t2 = head_reduce(t2); t3 = head_reduce(t3);

            float w0 = exp2f(t0);
            float w1 = exp2f(t1);
            float w2 = exp2f(t2);
            float w3 = exp2f(t3);
            sA_ += w0 + w1;
            sB_ += w2 + w3;
            a0A = fmaf(w0, xa0, fmaf(w1, xb0, a0A));
            a1A = fmaf(w0, xa1, fmaf(w1, xb1, a1A));
            a0B = fmaf(w2, xc0, fmaf(w3, xd0, a0B));
            a1B = fmaf(w2, xc1, fmaf(w3, xd1, a1B));
        }
        for (; idx < end; ++idx) {
            int off0 = cs_s[idx];
            const unsigned short* ep = ea_s + (size_t)idx * 16;
            uint4 qA = *reinterpret_cast<const uint4*>(ep);
            uint2 qC = *reinterpret_cast<const uint2*>(ep + 8);
            unsigned int xw0 = *reinterpret_cast<const unsigned int*>(xl_lane + off0);
            float2 el0 = edge_el(qA, qC, wx, wy);
            float xa0 = bflo(xw0), xa1 = bfhi(xw0);
            float tt = lrelu(xa0 + xr0 + el0.x) * av.x + lrelu(xa1 + xr1 + el0.y) * av.y;
            tt = head_reduce(tt);
            float w = exp2f(tt);
            sA_ += w;
            a0A = fmaf(w, xa0, a0A);
            a1A = fmaf(w, xa1, a1A);
        }
        float s  = sA_ + sB_;
        float a0 = a0A + a0B;
        float a1 = a1A + a1B;
        float inv = 1.f / s;   // s > 0 guaranteed by the self-loop
        float r0 = fmaf(a0, inv, bc.x);
        float r1 = fmaf(a1, inv, bc.y);
        *reinterpret_cast<float2*>(g + (size_t)n * 128 + f0) = make_float2(r0, r1);
        bs0 += r0; bs1 += r1;
        bq0 = fmaf(r0, r0, bq0); bq1 = fmaf(r1, r1, bq1);
    }

    // block-level BN stat reduction into slot (blockIdx & 31)
    __shared__ float red[256 * 4];
    int t = threadIdx.x;
    red[t * 4 + 0] = bs0; red[t * 4 + 1] = bs1;
    red[t * 4 + 2] = bq0; red[t * 4 + 3] = bq1;
    __syncthreads();
    if (t < 64) {
        float v0 = red[t * 4 + 0] + red[(t + 64) * 4 + 0] + red[(t + 128) * 4 + 0] + red[(t + 192) * 4 + 0];
        float v1 = red[t * 4 + 1] + red[(t + 64) * 4 + 1] + red[(t + 128) * 4 + 1] + red[(t + 192) * 4 + 1];
        float q0 = red[t * 4 + 2] + red[(t + 64) * 4 + 2] + red[(t + 128) * 4 + 2] + red[(t + 192) * 4 + 2];
        float q1 = red[t * 4 + 3] + red[(t + 64) * 4 + 3] + red[(t + 128) * 4 + 3] + red[(t + 192) * 4 + 3];
        float* slot = bnstat + (size_t)(blockIdx.x & (NSLOT - 1)) * 256;
        atomicAdd(&slot[2 * t + 0], v0);
        atomicAdd(&slot[2 * t + 1], v1);
        atomicAdd(&slot[128 + 2 * t + 0], q0);
        atomicAdd(&slot[128 + 2 * t + 1], q1);
    }
}

// ---------------- BN apply (odd layers only: + residual + relu) ----------------

__launch_bounds__(256)
__global__ void k_bnapply_res_relu(const float4* __restrict__ gin,
                                   const float* __restrict__ bnstat,
                                   const float* __restrict__ scale, const float* __restrict__ bias,
                                   float4* __restrict__ hbuf)
{
    __shared__ float sA[128], bA[128];
    int t = threadIdx.x;
    if (t < 128) {
        float sum = 0.f, sq = 0.f;
#pragma unroll
        for (int sl = 0; sl < NSLOT; sl++) {
            sum += bnstat[sl * 256 + t];
            sq  += bnstat[sl * 256 + 128 + t];
        }
        const float invN = 1.0f / (float)NN;
        float mean = sum * invN;
        float var  = sq * invN - mean * mean;
        float sc   = scale[t] * rsqrtf(var + 1e-5f);
        sA[t] = sc;
        bA[t] = bias[t] - mean * sc;
    }
    __syncthreads();
    int idx = blockIdx.x * 256 + t;
    int c4 = (idx & 31) * 4;
    float4 v = gin[idx];
    float4 hv = hbuf[idx];
    float4 r;
    r.x = fmaxf(fmaf(v.x, sA[c4 + 0], bA[c4 + 0]) + hv.x, 0.f);
    r.y = fmaxf(fmaf(v.y, sA[c4 + 1], bA[c4 + 1]) + hv.y, 0.f);
    r.z = fmaxf(fmaf(v.z, sA[c4 + 2], bA[c4 + 2]) + hv.z, 0.f);
    r.w = fmaxf(fmaf(v.w, sA[c4 + 3], bA[c4 + 3]) + hv.w, 0.f);
    hbuf[idx] = r;
}

// ---------------- pooling + value head ----------------

__launch_bounds__(128)
__global__ void k_pool(const float* __restrict__ h, const int* __restrict__ batch,
                       float* __restrict__ pooled, float* __restrict__ cnt)
{
    int c = threadIdx.x;
    int r0 = blockIdx.x * 128;
    int cur = batch[r0];
    float acc = 0.f;
    float run = 0.f;
    for (int i = 0; i < 128; ++i) {
        int r = r0 + i;
        int b = batch[r];
        if (b != cur) {
            atomicAdd(&pooled[(size_t)cur * 128 + c], acc);
            if (c == 0) atomicAdd(&cnt[cur], run);
            acc = 0.f; run = 0.f; cur = b;
        }
        acc += h[(size_t)r * 128 + c];
        run += 1.f;
    }
    atomicAdd(&pooled[(size_t)cur * 128 + c], acc);
    if (c == 0) atomicAdd(&cnt[cur], run);
}

__launch_bounds__(64)
__global__ void k_value(const float* __restrict__ pooled, const float* __restrict__ cnt,
                        const float* __restrict__ Wv1, const float* __restrict__ bv1,
                        const float* __restrict__ Wv2, const float* __restrict__ bv2,
                        float* __restrict__ out)
{
    int gi = blockIdx.x;
    int l = threadIdx.x;
    float inv = 1.f / fmaxf(cnt[gi], 1.f);
    const float* pr = pooled + (size_t)gi * 128;
    float z = bv1[l];
    for (int k = 0; k < 128; k++) z = fmaf(pr[k] * inv, Wv1[k * 64 + l], z);
    z = fmaxf(z, 0.f);
#pragma unroll
    for (int j = 0; j < 3; j++) {
        float p = z * Wv2[l * 3 + j];
        p += __shfl_xor(p, 32); p += __shfl_xor(p, 16); p += __shfl_xor(p, 8);
        p += __shfl_xor(p, 4);  p += __shfl_xor(p, 2);  p += __shfl_xor(p, 1);
        if (l == 0) out[gi * 3 + j] = p + bv2[j];
    }
}

// ---------------- policy head (P bf16; f16 edge-ordered attrs; 2-edge unroll; DPP) ----------------

__device__ __forceinline__ void dec12(uint4 A, uint2 C, float* o)
{
    __half2 h;
    h = *reinterpret_cast<__half2*>(&A.x); o[0] = __low2float(h); o[1]  = __high2float(h);
    h = *reinterpret_cast<__half2*>(&A.y); o[2] = __low2float(h); o[3]  = __high2float(h);
    h = *reinterpret_cast<__half2*>(&A.z); o[4] = __low2float(h); o[5]  = __high2float(h);
    h = *reinterpret_cast<__half2*>(&A.w); o[6] = __low2float(h); o[7]  = __high2float(h);
    h = *reinterpret_cast<__half2*>(&C.x); o[8] = __low2float(h); o[9]  = __high2float(h);
    h = *reinterpret_cast<__half2*>(&C.y); o[10] = __low2float(h); o[11] = __high2float(h);
}

__launch_bounds__(256)
__global__ void k_policy(const unsigned short* __restrict__ P,
                         const unsigned short* __restrict__ eaOrd,
                         const int* __restrict__ src0, const int* __restrict__ dst0,
                         const float* __restrict__ Wp1c, const float* __restrict__ bp1,
                         const float* __restrict__ Wp2, const float* __restrict__ bp2,
                         float* __restrict__ out)
{
    int wave = (blockIdx.x * 256 + threadIdx.x) >> 6;   // 16384 waves
    int lane = threadIdx.x & 63;
    const unsigned short* ea_s = (const unsigned short*)rfl64((unsigned long long)eaOrd);
    const int* s_s = (const int*)rfl64((unsigned long long)src0);
    const int* d_s = (const int*)rfl64((unsigned long long)dst0);
    float w1c[12];
#pragma unroll
    for (int k = 0; k < 12; k++) w1c[k] = Wp1c[k * 64 + lane];
    float wp2 = Wp2[lane];
    float bb = bp1[lane];
    float b2 = bp2[0];
    for (int i = 0; i < 8; i += 2) {
        int e0i = wave * 8 + i;
        int e1i = e0i + 1;
        int sI0 = s_s[e0i], dI0 = d_s[e0i];
        int sI1 = s_s[e1i], dI1 = d_s[e1i];
        const unsigned short* ep = ea_s + (size_t)e0i * 16;
        uint4 A0 = *reinterpret_cast<const uint4*>(ep);
        uint2 C0 = *reinterpret_cast<const uint2*>(ep + 8);
        uint4 A1 = *reinterpret_cast<const uint4*>(ep + 16);
        uint2 C1 = *reinterpret_cast<const uint2*>(ep + 24);
        unsigned short ps0 = P[(size_t)sI0 * 128 + lane];
        unsigned short pd0 = P[(size_t)dI0 * 128 + 64 + lane];
        unsigned short ps1 = P[(size_t)sI1 * 128 + lane];
        unsigned short pd1 = P[(size_t)dI1 * 128 + 64 + lane];

        float ea0[12], ea1[12];
        dec12(A0, C0, ea0);
        dec12(A1, C1, ea1);

        float z0 = bf2f(ps0) + bf2f(pd0) + bb;
        float z1 = bf2f(ps1) + bf2f(pd1) + bb;
#pragma unroll
        for (int k = 0; k < 12; k++) {
            z0 = fmaf(ea0[k], w1c[k], z0);
            z1 = fmaf(ea1[k], w1c[k], z1);
        }
        float p0 = fmaxf(z0, 0.f) * wp2;
        float p1 = fmaxf(z1, 0.f) * wp2;
        p0 = head_reduce(p0);
        p1 = head_reduce(p1);
        p0 += __shfl_xor(p0, 16); p1 += __shfl_xor(p1, 16);
        p0 += __shfl_xor(p0, 32); p1 += __shfl_xor(p1, 32);
        if (lane == 0) {
            out[3072 + e0i] = p0 + b2;
            out[3072 + e1i] = p1 + b2;
        }
    }
}

// ---------------- host ----------------

extern "C" void kernel_launch(void* const* d_in, const int* in_sizes, int n_in,
                              void* d_out, int out_size, void* d_ws, size_t ws_size,
                              hipStream_t stream)
{
    const float* x     = (const float*)d_in[0];
    const float* eattr = (const float*)d_in[1];
    const int*   eidx  = (const int*)d_in[2];
    const int*   batch = (const int*)d_in[3];
    const float* Win   = (const float*)d_in[4];
    const float* bin   = (const float*)d_in[5];
    const float* Wl    = (const float*)d_in[6];
    const float* Wr    = (const float*)d_in[7];
    const float* We    = (const float*)d_in[8];
    const float* att   = (const float*)d_in[9];
    const float* bconv = (const float*)d_in[10];
    const float* bnsc  = (const float*)d_in[11];
    const float* bnbi  = (const float*)d_in[12];
    const float* Wv1   = (const float*)d_in[13];
    const float* bv1   = (const float*)d_in[14];
    const float* Wv2   = (const float*)d_in[15];
    const float* bv2   = (const float*)d_in[16];
    const float* Wp1   = (const float*)d_in[17];
    const float* bp1   = (const float*)d_in[18];
    const float* Wp2   = (const float*)d_in[19];
    const float* bp2   = (const float*)d_in[20];
    float* out = (float*)d_out;

    const int* src0 = eidx;
    const int* dst0 = eidx + EE;

    const size_t NH = (size_t)NN * 128;
    float* ws = (float*)d_ws;
    float* h  = ws;                    // N*128 fp32
    float* g  = h + NH;                // N*128 fp32
    unsigned short* xlb = (unsigned short*)(g + NH);        // N*128 bf16 (reused as policy P)
    unsigned short* xrb = xlb + NH;                          // N*128 bf16
    unsigned short* eaCSR = xrb + NH;                        // EPX*16 f16 (32B/edge, padded)
    unsigned short* eaOrd = eaCSR + (size_t)EPX * 16;        // EE*16 f16 (edge order)
    int* rowptr = (int*)(eaOrd + (size_t)EE * 16);           // N+1
    int* csr_src = rowptr + (NN + 1);                        // EPX (byte offsets)
    // --- zeroed region (one memset) ---
    int* deg  = csr_src + EPX;         // N
    int* fill = deg + NN;              // N
    float* bnstat = (float*)(fill + NN);        // 8 layers * NSLOT * 256
    float* pooled = bnstat + 8 * NSLOT * 256;   // G*128
    float* cnt    = pooled + (size_t)GG * 128;  // G
    size_t zero_elems = (size_t)NN + NN + 8 * NSLOT * 256 + (size_t)GG * 128 + GG;
    // --- MFMA-swizzled weights (fully rewritten each launch) ---
    unsigned short* wg = (unsigned short*)(cnt + GG);   // 8*32768
    unsigned short* wp = wg + 8 * 32768;                // 16384

    hipMemsetAsync(deg, 0, zero_elems * sizeof(float), stream);

    // CSR build + weight prep
    k_deg<<<EE / 256, 256, 0, stream>>>(dst0, deg);
    k_scan<<<1, 1024, 0, stream>>>(deg, rowptr);
    k_scatter<<<EPX / 256, 256, 0, stream>>>(src0, dst0, eattr, rowptr, deg, fill,
                                             csr_src, eaCSR, eaOrd);
    k_selfattr<<<(NN * 16) / 256, 256, 0, stream>>>(rowptr, eaCSR);
    k_wprep<<<136, 256, 0, stream>>>(Wl, Wr, Wp1, wg, wp);

    // input layer
    k_input<<<NN / 16, 256, 0, stream>>>(x, Win, bin, h);

    // 8 GATv2 + BN layers (even: g->stats; odd: BN fused into GEMM A-load, then res+relu)
    for (int l = 0; l < 8; l++) {
        float* bs = bnstat + (size_t)l * NSLOT * 256;
        if (l % 2 == 0) {
            k_gemm_gat<<<NN / 64, 256, 0, stream>>>(h, wg + (size_t)l * 32768, xlb, xrb);
        } else {
            float* bsp = bnstat + (size_t)(l - 1) * NSLOT * 256;   // previous layer's stats
            k_gemm_gat_bn<<<NN / 64, 256, 0, stream>>>(g, bsp,
                                                       bnsc + (size_t)(l - 1) * 128,
                                                       bnbi + (size_t)(l - 1) * 128,
                                                       wg + (size_t)l * 32768, xlb, xrb);
        }
        k_gat<<<NN / 16, 256, 0, stream>>>(xlb, xrb, eaCSR, rowptr, csr_src,
                                           We + (size_t)l * 1536, att + (size_t)l * 128,
                                           bconv + (size_t)l * 128, g, bs);
        if (l % 2 == 1) {
            k_bnapply_res_relu<<<(NN * 128 / 4) / 256, 256, 0, stream>>>(
                (const float4*)g, bs, bnsc + (size_t)l * 128, bnbi + (size_t)l * 128,
                (float4*)h);
        }
    }

    // pooling + value head
    k_pool<<<NN / 128, 128, 0, stream>>>(h, batch, pooled, cnt);
    k_value<<<GG, 64, 0, stream>>>(pooled, cnt, Wv1, bv1, Wv2, bv2, out);

    // policy head (P stored bf16 in xlb; f16 edge-ordered attrs)
    unsigned short* P = xlb;
    k_gemm_pol<<<NN / 64, 256, 0, stream>>>(h, wp, P);
    k_policy<<<NN / 4, 256, 0, stream>>>(P, eaOrd, src0, dst0,
                                         Wp1 + 256 * 64, bp1, Wp2, bp2, out);
}

// Round 16
// 1041.458 us; speedup vs baseline: 1.1225x; 1.0385x over previous
//
#include <hip/hip_runtime.h>
#include <hip/hip_fp16.h>

#define NN 65536
#define EE 524288
#define EPX 589824   // EE + NN
#define GG 1024
#define NSLOT 32     // BN stat slot copies (breaks atomic contention)

typedef __attribute__((ext_vector_type(8))) short bf16x8;
typedef __attribute__((ext_vector_type(4))) float f32x4;
typedef _Float16 f16x2 __attribute__((ext_vector_type(2)));

#define LOG2E 1.44269504088896f

#if __has_builtin(__builtin_amdgcn_fdot2)
#define HAVE_FDOT2 1
#endif

// ---------------- bf16/f16 helpers ----------------

__device__ __forceinline__ unsigned short f2bf(float x) {
    unsigned int u = __float_as_uint(x);
    u += 0x7FFFu + ((u >> 16) & 1u);      // round-to-nearest-even
    return (unsigned short)(u >> 16);
}
__device__ __forceinline__ float bflo(unsigned int w) { return __uint_as_float(w << 16); }
__device__ __forceinline__ float bfhi(unsigned int w) { return __uint_as_float(w & 0xFFFF0000u); }
__device__ __forceinline__ float bf2f(unsigned short u) { return __uint_as_float((unsigned int)u << 16); }
__device__ __forceinline__ float lrelu(float x) { return fmaf(0.4f, fabsf(x), 0.6f * x); }
__device__ __forceinline__ unsigned int packh2(float a, float b) {
    __half2 h = __floats2half2_rn(a, b);
    return *reinterpret_cast<unsigned int*>(&h);
}
__device__ __forceinline__ f16x2 as_f16x2(unsigned int u) {
    union { unsigned int u; f16x2 h; } c; c.u = u; return c.h;
}
__device__ __forceinline__ float fdot2p(unsigned int e, f16x2 w, float acc) {
#ifdef HAVE_FDOT2
    return __builtin_amdgcn_fdot2(as_f16x2(e), w, acc, false);
#else
    __half2 h = *reinterpret_cast<__half2*>(&e);
    return acc + __low2float(h) * (float)w[0] + __high2float(h) * (float)w[1];
#endif
}
__device__ __forceinline__ unsigned long long rfl64(unsigned long long v) {
    unsigned int lo = __builtin_amdgcn_readfirstlane((unsigned int)v);
    unsigned int hi = __builtin_amdgcn_readfirstlane((unsigned int)(v >> 32));
    return (((unsigned long long)hi) << 32) | lo;
}

// DPP-based in-row reduce: sum over each 16-lane row, result in all 16 lanes. Pure VALU.
template <int CTRL>
__device__ __forceinline__ float dpp_add(float v) {
    int x = __builtin_amdgcn_update_dpp(0, __float_as_int(v), CTRL, 0xf, 0xf, true);
    return v + __int_as_float(x);
}
__device__ __forceinline__ float head_reduce(float t) {
    t = dpp_add<0xB1>(t);    // quad_perm [1,0,3,2]  (xor 1)
    t = dpp_add<0x4E>(t);    // quad_perm [2,3,0,1]  (xor 2)
    t = dpp_add<0x124>(t);   // row_ror:4
    t = dpp_add<0x128>(t);   // row_ror:8  -> full 16-lane sum
    return t;
}

// ---------------- CSR build ----------------

__launch_bounds__(256)
__global__ void k_deg(const int* __restrict__ dst0, int* __restrict__ deg)
{
    int e = blockIdx.x * 256 + threadIdx.x;
    if (e >= EE) return;
    atomicAdd(&deg[dst0[e]], 1);
}

__launch_bounds__(1024)
__global__ void k_scan(const int* __restrict__ deg, int* __restrict__ rowptr)
{
    __shared__ int sums[1024];
    int t = threadIdx.x;
    int base = t * 64;
    int s = 0;
    for (int i = 0; i < 64; i++) s += deg[base + i] + 1;
    sums[t] = s;
    __syncthreads();
    for (int off = 1; off < 1024; off <<= 1) {
        int v = (t >= off) ? sums[t - off] : 0;
        __syncthreads();
        sums[t] += v;
        __syncthreads();
    }
    int off = sums[t] - s;   // exclusive prefix
    for (int i = 0; i < 64; i++) { rowptr[base + i] = off; off += deg[base + i] + 1; }
    if (t == 1023) rowptr[NN] = off;
}

// scatter edges into CSR order; attrs -> f16 padded 32B/edge in CSR order AND in
// original edge order (eaOrd, for the policy head). csr_src holds BYTE offsets.
__launch_bounds__(256)
__global__ void k_scatter(const int* __restrict__ src0, const int* __restrict__ dst0,
                          const float* __restrict__ eattr,
                          const int* __restrict__ rowptr, const int* __restrict__ deg,
                          int* __restrict__ fill, int* __restrict__ csr_src,
                          unsigned short* __restrict__ eaCSR,
                          unsigned short* __restrict__ eaOrd)
{
    int e = blockIdx.x * 256 + threadIdx.x;
    if (e >= EPX) return;
    if (e < EE) {
        int d = dst0[e];
        int pos = rowptr[d] + atomicAdd(&fill[d], 1);
        csr_src[pos] = src0[e] << 8;   // byte offset into bf16 row (128*2B)
        const float* ep = eattr + (size_t)e * 12;
        float4 a = *reinterpret_cast<const float4*>(ep);
        float4 b = *reinterpret_cast<const float4*>(ep + 4);
        float4 c = *reinterpret_cast<const float4*>(ep + 8);
        uint4 w; w.x = packh2(a.x, a.y); w.y = packh2(a.z, a.w);
        w.z = packh2(b.x, b.y); w.w = packh2(b.z, b.w);
        uint2 w2 = make_uint2(packh2(c.x, c.y), packh2(c.z, c.w));
        unsigned short* o = eaCSR + (size_t)pos * 16;
        *reinterpret_cast<uint4*>(o) = w;
        *reinterpret_cast<uint2*>(o + 8) = w2;
        unsigned short* o2 = eaOrd + (size_t)e * 16;
        *reinterpret_cast<uint4*>(o2) = w;
        *reinterpret_cast<uint2*>(o2 + 8) = w2;
    } else {
        int n = e - EE;
        csr_src[rowptr[n] + deg[n]] = n << 8;   // self-loop in the last slot
    }
}

// fill each node's self-loop attr slot with the mean of its real incoming edge attrs.
__launch_bounds__(256)
__global__ void k_selfattr(const int* __restrict__ rowptr, unsigned short* __restrict__ eaCSR)
{
    int tid = blockIdx.x * 256 + threadIdx.x;   // NN*16 threads
    int n = tid >> 4;
    int lk = tid & 15;
    if (lk >= 12) return;
    int beg = rowptr[n], endm1 = rowptr[n + 1] - 1;
    float s = 0.f;
    for (int p = beg; p < endm1; ++p) {
        __half h = *reinterpret_cast<const __half*>(&eaCSR[(size_t)p * 16 + lk]);
        s += __half2float(h);
    }
    float dv = fmaxf((float)(endm1 - beg), 1.0f);
    __half ho = __float2half(s / dv);
    eaCSR[(size_t)endm1 * 16 + lk] = *reinterpret_cast<unsigned short*>(&ho);
}

// ---------------- MFMA weight prep: swizzle W into 16x16x32 B-fragment order ----------------

__launch_bounds__(256)
__global__ void k_wprep(const float* __restrict__ Wl, const float* __restrict__ Wr,
                        const float* __restrict__ Wp1,
                        unsigned short* __restrict__ wg, unsigned short* __restrict__ wp)
{
    int tid = blockIdx.x * 256 + threadIdx.x;   // 34816 threads
    if (tid < 32768) {
        int l = tid >> 12;
        int r = tid & 4095;
        int kt = r >> 10, ct = (r >> 6) & 15, lane = r & 63;
        int kb = kt * 32 + (lane >> 4) * 8;
        int col = ct * 16 + (lane & 15);
        const float* W = (col < 128) ? (Wl + (size_t)l * 16384 + col)
                                     : (Wr + (size_t)l * 16384 + (col - 128));
        unsigned short* o = wg + (size_t)tid * 8;
#pragma unroll
        for (int j = 0; j < 8; j++) o[j] = f2bf(W[(size_t)(kb + j) * 128]);
    } else if (tid < 34816) {
        int r = tid - 32768;
        int kt = r >> 9, ct = (r >> 6) & 7, lane = r & 63;
        int kb = kt * 32 + (lane >> 4) * 8;
        int col = ct * 16 + (lane & 15);
        const float* W = (col < 64) ? (Wp1 + col) : (Wp1 + 128 * 64 + (col - 64));
        unsigned short* o = wp + (size_t)r * 8;
#pragma unroll
        for (int j = 0; j < 8; j++) o[j] = f2bf(W[(size_t)(kb + j) * 64]);
    }
}

// ---------------- input layer: h = relu(x @ Win + bin) ----------------

__launch_bounds__(256)
__global__ void k_input(const float* __restrict__ x, const float* __restrict__ Win,
                        const float* __restrict__ bin, float* __restrict__ h)
{
    __shared__ float W[21 * 128];
    int t = threadIdx.x;
    for (int i = t; i < 21 * 128; i += 256) W[i] = Win[i];
    __syncthreads();
    int c = t & 127, sub = t >> 7;
    int n0 = blockIdx.x * 16;
    float bc = bin[c];
    for (int i = 0; i < 8; i++) {
        int n = n0 + sub + i * 2;
        const float* xp = x + (size_t)n * 21;
        float acc = bc;
#pragma unroll
        for (int k = 0; k < 21; k++) acc = fmaf(xp[k], W[k * 128 + c], acc);
        h[(size_t)n * 128 + c] = fmaxf(acc, 0.f);
    }
}

// ---------------- MFMA GEMMs (no LDS; A fp32 -> bf16 in-register; B pre-swizzled) ----------------

__device__ __forceinline__ void load_afrag(const float* __restrict__ A, int arow, int kb,
                                           bf16x8 af[4])
{
#pragma unroll
    for (int kt = 0; kt < 4; kt++) {
        const float* ap = A + (size_t)arow * 128 + kt * 32 + kb;
        float4 lo = *reinterpret_cast<const float4*>(ap);
        float4 hi = *reinterpret_cast<const float4*>(ap + 4);
        bf16x8 v;
        v[0] = (short)f2bf(lo.x); v[1] = (short)f2bf(lo.y);
        v[2] = (short)f2bf(lo.z); v[3] = (short)f2bf(lo.w);
        v[4] = (short)f2bf(hi.x); v[5] = (short)f2bf(hi.y);
        v[6] = (short)f2bf(hi.z); v[7] = (short)f2bf(hi.w);
        af[kt] = v;
    }
}

__device__ __forceinline__ void gemm_gat_core(const bf16x8 af[4], const unsigned short* __restrict__ Bf,
                                              int row0, unsigned short* __restrict__ Cl,
                                              unsigned short* __restrict__ Cr, int lane)
{
    int crow = row0 + (lane >> 4) * 4;
    int c0 = lane & 15;
#pragma unroll
    for (int ct = 0; ct < 16; ct++) {
        f32x4 acc = {0.f, 0.f, 0.f, 0.f};
#pragma unroll
        for (int kt = 0; kt < 4; kt++) {
            bf16x8 bf = *reinterpret_cast<const bf16x8*>(Bf + ((size_t)(kt * 16 + ct) * 64 + lane) * 8);
            acc = __builtin_amdgcn_mfma_f32_16x16x32_bf16(af[kt], bf, acc, 0, 0, 0);
        }
        int col = ct * 16 + c0;
        unsigned short* C = (col < 128) ? Cl : Cr;
        int cc = col & 127;
#pragma unroll
        for (int r = 0; r < 4; r++)
            C[(size_t)(crow + r) * 128 + cc] = f2bf(acc[r]);
    }
}

// xl|xr = h @ [Wl|Wr], plain fp32 A
__launch_bounds__(256)
__global__ void k_gemm_gat(const float* __restrict__ A, const unsigned short* __restrict__ Bf,
                           unsigned short* __restrict__ Cl, unsigned short* __restrict__ Cr)
{
    int wave = threadIdx.x >> 6, lane = threadIdx.x & 63;
    int row0 = blockIdx.x * 64 + wave * 16;
    bf16x8 af[4];
    load_afrag(A, row0 + (lane & 15), (lane >> 4) * 8, af);
    gemm_gat_core(af, Bf, row0, Cl, Cr, lane);
}

__device__ __forceinline__ void bn_coeff_lds(const float* __restrict__ bnstat,
                                             const float* __restrict__ scale,
                                             const float* __restrict__ bias,
                                             float* sA, float* bA)
{
    int t = threadIdx.x;
    if (t < 128) {
        float sum = 0.f, sq = 0.f;
#pragma unroll
        for (int sl = 0; sl < NSLOT; sl++) {
            sum += bnstat[sl * 256 + t];
            sq  += bnstat[sl * 256 + 128 + t];
        }
        const float invN = 1.0f / (float)NN;
        float mean = sum * invN;
        float var  = sq * invN - mean * mean;
        float sc   = scale[t] * rsqrtf(var + 1e-5f);
        sA[t] = sc;
        bA[t] = bias[t] - mean * sc;
    }
    __syncthreads();
}

// xl|xr = relu(bn(g)) @ [Wl|Wr]: BN coeffs from slotted stats, applied on the A-load.
__launch_bounds__(256)
__global__ void k_gemm_gat_bn(const float* __restrict__ G, const float* __restrict__ bnstat,
                              const float* __restrict__ scale, const float* __restrict__ bias,
                              const unsigned short* __restrict__ Bf,
                              unsigned short* __restrict__ Cl, unsigned short* __restrict__ Cr)
{
    __shared__ float sA[128], bA[128];
    bn_coeff_lds(bnstat, scale, bias, sA, bA);
    int t = threadIdx.x;
    int wave = t >> 6, lane = t & 63;
    int row0 = blockIdx.x * 64 + wave * 16;
    int arow = row0 + (lane & 15);
    int kb = (lane >> 4) * 8;
    bf16x8 af[4];
#pragma unroll
    for (int kt = 0; kt < 4; kt++) {
        int cb = kt * 32 + kb;
        const float* gp = G + (size_t)arow * 128 + cb;
        float4 lo = *reinterpret_cast<const float4*>(gp);
        float4 hi = *reinterpret_cast<const float4*>(gp + 4);
        bf16x8 v;
        v[0] = (short)f2bf(fmaxf(fmaf(lo.x, sA[cb + 0], bA[cb + 0]), 0.f));
        v[1] = (short)f2bf(fmaxf(fmaf(lo.y, sA[cb + 1], bA[cb + 1]), 0.f));
        v[2] = (short)f2bf(fmaxf(fmaf(lo.z, sA[cb + 2], bA[cb + 2]), 0.f));
        v[3] = (short)f2bf(fmaxf(fmaf(lo.w, sA[cb + 3], bA[cb + 3]), 0.f));
        v[4] = (short)f2bf(fmaxf(fmaf(hi.x, sA[cb + 4], bA[cb + 4]), 0.f));
        v[5] = (short)f2bf(fmaxf(fmaf(hi.y, sA[cb + 5], bA[cb + 5]), 0.f));
        v[6] = (short)f2bf(fmaxf(fmaf(hi.z, sA[cb + 6], bA[cb + 6]), 0.f));
        v[7] = (short)f2bf(fmaxf(fmaf(hi.w, sA[cb + 7], bA[cb + 7]), 0.f));
        af[kt] = v;
    }
    gemm_gat_core(af, Bf, row0, Cl, Cr, lane);
}

// even layers 2/4/6: h = relu(bn(g) + h) computed in the A-load, written back to h,
// then xl|xr = h @ [Wl|Wr]. Replaces the separate k_bnapply_res_relu pass.
__launch_bounds__(256)
__global__ void k_gemm_gat_bnres(const float* __restrict__ G, const float* __restrict__ bnstat,
                                 const float* __restrict__ scale, const float* __restrict__ bias,
                                 float* __restrict__ H, const unsigned short* __restrict__ Bf,
                                 unsigned short* __restrict__ Cl, unsigned short* __restrict__ Cr)
{
    __shared__ float sA[128], bA[128];
    bn_coeff_lds(bnstat, scale, bias, sA, bA);
    int t = threadIdx.x;
    int wave = t >> 6, lane = t & 63;
    int row0 = blockIdx.x * 64 + wave * 16;
    int arow = row0 + (lane & 15);
    int kb = (lane >> 4) * 8;
    bf16x8 af[4];
#pragma unroll
    for (int kt = 0; kt < 4; kt++) {
        int cb = kt * 32 + kb;
        const float* gp = G + (size_t)arow * 128 + cb;
        float* hp = H + (size_t)arow * 128 + cb;
        float4 glo = *reinterpret_cast<const float4*>(gp);
        float4 ghi = *reinterpret_cast<const float4*>(gp + 4);
        float4 hlo = *reinterpret_cast<const float4*>(hp);
        float4 hhi = *reinterpret_cast<const float4*>(hp + 4);
        float4 nlo, nhi;
        nlo.x = fmaxf(fmaf(glo.x, sA[cb + 0], bA[cb + 0]) + hlo.x, 0.f);
        nlo.y = fmaxf(fmaf(glo.y, sA[cb + 1], bA[cb + 1]) + hlo.y, 0.f);
        nlo.z = fmaxf(fmaf(glo.z, sA[cb + 2], bA[cb + 2]) + hlo.z, 0.f);
        nlo.w = fmaxf(fmaf(glo.w, sA[cb + 3], bA[cb + 3]) + hlo.w, 0.f);
        nhi.x = fmaxf(fmaf(ghi.x, sA[cb + 4], bA[cb + 4]) + hhi.x, 0.f);
        nhi.y = fmaxf(fmaf(ghi.y, sA[cb + 5], bA[cb + 5]) + hhi.y, 0.f);
        nhi.z = fmaxf(fmaf(ghi.z, sA[cb + 6], bA[cb + 6]) + hhi.z, 0.f);
        nhi.w = fmaxf(fmaf(ghi.w, sA[cb + 7], bA[cb + 7]) + hhi.w, 0.f);
        *reinterpret_cast<float4*>(hp) = nlo;
        *reinterpret_cast<float4*>(hp + 4) = nhi;
        bf16x8 v;
        v[0] = (short)f2bf(nlo.x); v[1] = (short)f2bf(nlo.y);
        v[2] = (short)f2bf(nlo.z); v[3] = (short)f2bf(nlo.w);
        v[4] = (short)f2bf(nhi.x); v[5] = (short)f2bf(nhi.y);
        v[6] = (short)f2bf(nhi.z); v[7] = (short)f2bf(nhi.w);
        af[kt] = v;
    }
    gemm_gat_core(af, Bf, row0, Cl, Cr, lane);
}

// policy projections: P (bf16, N x 128) = A[N,128] @ B[128,128]
__launch_bounds__(256)
__global__ void k_gemm_pol(const float* __restrict__ A, const unsigned short* __restrict__ Bf,
                           unsigned short* __restrict__ P)
{
    int wave = threadIdx.x >> 6, lane = threadIdx.x & 63;
    int row0 = blockIdx.x * 64 + wave * 16;
    bf16x8 af[4];
    load_afrag(A, row0 + (lane & 15), (lane >> 4) * 8, af);
    int crow = row0 + (lane >> 4) * 4;
    int c0 = lane & 15;
#pragma unroll
    for (int ct = 0; ct < 8; ct++) {
        f32x4 acc = {0.f, 0.f, 0.f, 0.f};
#pragma unroll
        for (int kt = 0; kt < 4; kt++) {
            bf16x8 bf = *reinterpret_cast<const bf16x8*>(Bf + ((size_t)(kt * 8 + ct) * 64 + lane) * 8);
            acc = __builtin_amdgcn_mfma_f32_16x16x32_bf16(af[kt], bf, acc, 0, 0, 0);
        }
        int col = ct * 16 + c0;
#pragma unroll
        for (int r = 0; r < 4; r++)
            P[(size_t)(crow + r) * 128 + col] = f2bf(acc[r]);
    }
}

// ---------------- GATv2 edge aggregation + fused BN stats (slotted) ----------------
// one wave per 4 consecutive dst nodes; no-max softmax; DPP head reduce; fdot2 el.

__device__ __forceinline__ float2 edge_el(uint4 A, uint2 C,
                                          const f16x2 wx[6], const f16x2 wy[6])
{
    float ex = fdot2p(A.x, wx[0], 0.f);
    ex = fdot2p(A.y, wx[1], ex);
    ex = fdot2p(A.z, wx[2], ex);
    ex = fdot2p(A.w, wx[3], ex);
    ex = fdot2p(C.x, wx[4], ex);
    ex = fdot2p(C.y, wx[5], ex);
    float ey = fdot2p(A.x, wy[0], 0.f);
    ey = fdot2p(A.y, wy[1], ey);
    ey = fdot2p(A.z, wy[2], ey);
    ey = fdot2p(A.w, wy[3], ey);
    ey = fdot2p(C.x, wy[4], ey);
    ey = fdot2p(C.y, wy[5], ey);
    float2 r; r.x = ex; r.y = ey;
    return r;
}

__launch_bounds__(256)
__global__ void k_gat(const unsigned short* __restrict__ xlb, const unsigned short* __restrict__ xrb,
                      const unsigned short* __restrict__ eaCSR,
                      const int* __restrict__ rowptr, const int* __restrict__ csr_src,
                      const float* __restrict__ We, const float* __restrict__ att,
                      const float* __restrict__ bconv, float* __restrict__ g,
                      float* __restrict__ bnstat)
{
    int wid = blockIdx.x * 4 + (threadIdx.x >> 6);   // 16384 waves, 4 nodes each
    int lane = threadIdx.x & 63;
    int f0 = lane * 2;

    const int* cs_s = (const int*)rfl64((unsigned long long)csr_src);
    const unsigned short* ea_s = (const unsigned short*)rfl64((unsigned long long)eaCSR);

    f16x2 wx[6], wy[6];
#pragma unroll
    for (int j = 0; j < 6; j++) {
        float2 w0 = *reinterpret_cast<const float2*>(We + (2 * j) * 128 + f0);
        float2 w1 = *reinterpret_cast<const float2*>(We + (2 * j + 1) * 128 + f0);
        wx[j] = (f16x2){(_Float16)w0.x, (_Float16)w1.x};
        wy[j] = (f16x2){(_Float16)w0.y, (_Float16)w1.y};
    }
    float2 av = *reinterpret_cast<const float2*>(att + f0);
    av.x *= LOG2E; av.y *= LOG2E;          // base-2 logits
    float2 bc = *reinterpret_cast<const float2*>(bconv + f0);
    const char* xl_lane = reinterpret_cast<const char*>(xlb) + (lane << 2);

    float bs0 = 0.f, bs1 = 0.f, bq0 = 0.f, bq1 = 0.f;   // BN partial stats

    for (int n = wid * 4; n < wid * 4 + 4; ++n) {
        unsigned int xrw = *reinterpret_cast<const unsigned int*>(xrb + (size_t)n * 128 + f0);
        float xr0 = bflo(xrw), xr1 = bfhi(xrw);

        float sA_ = 0.f, a0A = 0.f, a1A = 0.f;
        float sB_ = 0.f, a0B = 0.f, a1B = 0.f;
        int beg = rowptr[n], end = rowptr[n + 1];
        int idx = beg;
        for (; idx + 4 <= end; idx += 4) {
            int off0 = cs_s[idx],     off1 = cs_s[idx + 1];
            int off2 = cs_s[idx + 2], off3 = cs_s[idx + 3];
            const unsigned short* ep = ea_s + (size_t)idx * 16;
            uint4 qA = *reinterpret_cast<const uint4*>(ep);
            uint2 qC = *reinterpret_cast<const uint2*>(ep + 8);
            uint4 rA = *reinterpret_cast<const uint4*>(ep + 16);
            uint2 rC = *reinterpret_cast<const uint2*>(ep + 24);
            uint4 sAq = *reinterpret_cast<const uint4*>(ep + 32);
            uint2 sC = *reinterpret_cast<const uint2*>(ep + 40);
            uint4 tA = *reinterpret_cast<const uint4*>(ep + 48);
            uint2 tC = *reinterpret_cast<const uint2*>(ep + 56);
            unsigned int xw0 = *reinterpret_cast<const unsigned int*>(xl_lane + off0);
            unsigned int xw1 = *reinterpret_cast<const unsigned int*>(xl_lane + off1);
            unsigned int xw2 = *reinterpret_cast<const unsigned int*>(xl_lane + off2);
            unsigned int xw3 = *reinterpret_cast<const unsigned int*>(xl_lane + off3);

            float2 el0 = edge_el(qA, qC, wx, wy);
            float2 el1 = edge_el(rA, rC, wx, wy);
            float2 el2 = edge_el(sAq, sC, wx, wy);
            float2 el3 = edge_el(tA, tC, wx, wy);

            float xa0 = bflo(xw0), xa1 = bfhi(xw0);
            float xb0 = bflo(xw1), xb1 = bfhi(xw1);
            float xc0 = bflo(xw2), xc1 = bfhi(xw2);
            float xd0 = bflo(xw3), xd1 = bfhi(xw3);

            float t0 = lrelu(xa0 + xr0 + el0.x) * av.x + lrelu(xa1 + xr1 + el0.y) * av.y;
            float t1 = lrelu(xb0 + xr0 + el1.x) * av.x + lrelu(xb1 + xr1 + el1.y) * av.y;
            float t2 = lrelu(xc0 + xr0 + el2.x) * av.x + lrelu(xc1 + xr1 + el2.y) * av.y;
            float t3 = lrelu(xd0 + xr0 + el3.x) * av.x + lrelu(xd1 + xr1 + el3.y) * av.y;
            t0 = head_reduce(t0); t1 = head_reduce(t1);
            t2 = head_reduce(t2); t3 = head_reduce(t3);

            float w0 = exp2f(t0);
            float w1 = exp2f(t1);
            float w2 = exp2f(t2);
            float w3 = exp2f(t3);
            sA_ += w0 + w1;
            sB_ += w2 + w3;
            a0A = fmaf(w0, xa0, fmaf(w1, xb0, a0A));
            a1A = fmaf(w0, xa1, fmaf(w1, xb1, a1A));
            a0B = fmaf(w2, xc0, fmaf(w3, xd0, a0B));
            a1B = fmaf(w2, xc1, fmaf(w3, xd1, a1B));
        }
        for (; idx < end; ++idx) {
            int off0 = cs_s[idx];
            const unsigned short* ep = ea_s + (size_t)idx * 16;
            uint4 qA = *reinterpret_cast<const uint4*>(ep);
            uint2 qC = *reinterpret_cast<const uint2*>(ep + 8);
            unsigned int xw0 = *reinterpret_cast<const unsigned int*>(xl_lane + off0);
            float2 el0 = edge_el(qA, qC, wx, wy);
            float xa0 = bflo(xw0), xa1 = bfhi(xw0);
            float tt = lrelu(xa0 + xr0 + el0.x) * av.x + lrelu(xa1 + xr1 + el0.y) * av.y;
            tt = head_reduce(tt);
            float w = exp2f(tt);
            sA_ += w;
            a0A = fmaf(w, xa0, a0A);
            a1A = fmaf(w, xa1, a1A);
        }
        float s  = sA_ + sB_;
        float a0 = a0A + a0B;
        float a1 = a1A + a1B;
        float inv = 1.f / s;   // s > 0 guaranteed by the self-loop
        float r0 = fmaf(a0, inv, bc.x);
        float r1 = fmaf(a1, inv, bc.y);
        *reinterpret_cast<float2*>(g + (size_t)n * 128 + f0) = make_float2(r0, r1);
        bs0 += r0; bs1 += r1;
        bq0 = fmaf(r0, r0, bq0); bq1 = fmaf(r1, r1, bq1);
    }

    // block-level BN stat reduction into slot (blockIdx & 31)
    __shared__ float red[256 * 4];
    int t = threadIdx.x;
    red[t * 4 + 0] = bs0; red[t * 4 + 1] = bs1;
    red[t * 4 + 2] = bq0; red[t * 4 + 3] = bq1;
    __syncthreads();
    if (t < 64) {
        float v0 = red[t * 4 + 0] + red[(t + 64) * 4 + 0] + red[(t + 128) * 4 + 0] + red[(t + 192) * 4 + 0];
        float v1 = red[t * 4 + 1] + red[(t + 64) * 4 + 1] + red[(t + 128) * 4 + 1] + red[(t + 192) * 4 + 1];
        float q0 = red[t * 4 + 2] + red[(t + 64) * 4 + 2] + red[(t + 128) * 4 + 2] + red[(t + 192) * 4 + 2];
        float q1 = red[t * 4 + 3] + red[(t + 64) * 4 + 3] + red[(t + 128) * 4 + 3] + red[(t + 192) * 4 + 3];
        float* slot = bnstat + (size_t)(blockIdx.x & (NSLOT - 1)) * 256;
        atomicAdd(&slot[2 * t + 0], v0);
        atomicAdd(&slot[2 * t + 1], v1);
        atomicAdd(&slot[128 + 2 * t + 0], q0);
        atomicAdd(&slot[128 + 2 * t + 1], q1);
    }
}

// ---------------- BN apply (layer 7 only: + residual + relu) ----------------

__launch_bounds__(256)
__global__ void k_bnapply_res_relu(const float4* __restrict__ gin,
                                   const float* __restrict__ bnstat,
                                   const float* __restrict__ scale, const float* __restrict__ bias,
                                   float4* __restrict__ hbuf)
{
    __shared__ float sA[128], bA[128];
    bn_coeff_lds(bnstat, scale, bias, sA, bA);
    int t = threadIdx.x;
    int idx = blockIdx.x * 256 + t;
    int c4 = (idx & 31) * 4;
    float4 v = gin[idx];
    float4 hv = hbuf[idx];
    float4 r;
    r.x = fmaxf(fmaf(v.x, sA[c4 + 0], bA[c4 + 0]) + hv.x, 0.f);
    r.y = fmaxf(fmaf(v.y, sA[c4 + 1], bA[c4 + 1]) + hv.y, 0.f);
    r.z = fmaxf(fmaf(v.z, sA[c4 + 2], bA[c4 + 2]) + hv.z, 0.f);
    r.w = fmaxf(fmaf(v.w, sA[c4 + 3], bA[c4 + 3]) + hv.w, 0.f);
    hbuf[idx] = r;
}

// ---------------- pooling + value head ----------------

__launch_bounds__(128)
__global__ void k_pool(const float* __restrict__ h, const int* __restrict__ batch,
                       float* __restrict__ pooled, float* __restrict__ cnt)
{
    int c = threadIdx.x;
    int r0 = blockIdx.x * 128;
    int cur = batch[r0];
    float acc = 0.f;
    float run = 0.f;
    for (int i = 0; i < 128; ++i) {
        int r = r0 + i;
        int b = batch[r];
        if (b != cur) {
            atomicAdd(&pooled[(size_t)cur * 128 + c], acc);
            if (c == 0) atomicAdd(&cnt[cur], run);
            acc = 0.f; run = 0.f; cur = b;
        }
        acc += h[(size_t)r * 128 + c];
        run += 1.f;
    }
    atomicAdd(&pooled[(size_t)cur * 128 + c], acc);
    if (c == 0) atomicAdd(&cnt[cur], run);
}

__launch_bounds__(64)
__global__ void k_value(const float* __restrict__ pooled, const float* __restrict__ cnt,
                        const float* __restrict__ Wv1, const float* __restrict__ bv1,
                        const float* __restrict__ Wv2, const float* __restrict__ bv2,
                        float* __restrict__ out)
{
    int gi = blockIdx.x;
    int l = threadIdx.x;
    float inv = 1.f / fmaxf(cnt[gi], 1.f);
    const float* pr = pooled + (size_t)gi * 128;
    float z = bv1[l];
    for (int k = 0; k < 128; k++) z = fmaf(pr[k] * inv, Wv1[k * 64 + l], z);
    z = fmaxf(z, 0.f);
#pragma unroll
    for (int j = 0; j < 3; j++) {
        float p = z * Wv2[l * 3 + j];
        p += __shfl_xor(p, 32); p += __shfl_xor(p, 16); p += __shfl_xor(p, 8);
        p += __shfl_xor(p, 4);  p += __shfl_xor(p, 2);  p += __shfl_xor(p, 1);
        if (l == 0) out[gi * 3 + j] = p + bv2[j];
    }
}

// ---------------- policy head (P bf16; f16 attrs via fdot2; 2-edge unroll; DPP) ----------------

__launch_bounds__(256)
__global__ void k_policy(const unsigned short* __restrict__ P,
                         const unsigned short* __restrict__ eaOrd,
                         const int* __restrict__ src0, const int* __restrict__ dst0,
                         const float* __restrict__ Wp1c, const float* __restrict__ bp1,
                         const float* __restrict__ Wp2, const float* __restrict__ bp2,
                         float* __restrict__ out)
{
    int wave = (blockIdx.x * 256 + threadIdx.x) >> 6;   // 16384 waves
    int lane = threadIdx.x & 63;
    const unsigned short* ea_s = (const unsigned short*)rfl64((unsigned long long)eaOrd);
    const int* s_s = (const int*)rfl64((unsigned long long)src0);
    const int* d_s = (const int*)rfl64((unsigned long long)dst0);
    f16x2 w1h[6];
#pragma unroll
    for (int j = 0; j < 6; j++)
        w1h[j] = (f16x2){(_Float16)Wp1c[(2 * j) * 64 + lane], (_Float16)Wp1c[(2 * j + 1) * 64 + lane]};
    float wp2 = Wp2[lane];
    float bb = bp1[lane];
    float b2 = bp2[0];
    for (int i = 0; i < 8; i += 2) {
        int e0i = wave * 8 + i;
        int e1i = e0i + 1;
        int sI0 = s_s[e0i], dI0 = d_s[e0i];
        int sI1 = s_s[e1i], dI1 = d_s[e1i];
        const unsigned short* ep = ea_s + (size_t)e0i * 16;
        uint4 A0 = *reinterpret_cast<const uint4*>(ep);
        uint2 C0 = *reinterpret_cast<const uint2*>(ep + 8);
        uint4 A1 = *reinterpret_cast<const uint4*>(ep + 16);
        uint2 C1 = *reinterpret_cast<const uint2*>(ep + 24);
        unsigned short ps0 = P[(size_t)sI0 * 128 + lane];
        unsigned short pd0 = P[(size_t)dI0 * 128 + 64 + lane];
        unsigned short ps1 = P[(size_t)sI1 * 128 + lane];
        unsigned short pd1 = P[(size_t)dI1 * 128 + 64 + lane];

        float z0 = bf2f(ps0) + bf2f(pd0) + bb;
        z0 = fdot2p(A0.x, w1h[0], z0); z0 = fdot2p(A0.y, w1h[1], z0);
        z0 = fdot2p(A0.z, w1h[2], z0); z0 = fdot2p(A0.w, w1h[3], z0);
        z0 = fdot2p(C0.x, w1h[4], z0); z0 = fdot2p(C0.y, w1h[5], z0);
        float z1 = bf2f(ps1) + bf2f(pd1) + bb;
        z1 = fdot2p(A1.x, w1h[0], z1); z1 = fdot2p(A1.y, w1h[1], z1);
        z1 = fdot2p(A1.z, w1h[2], z1); z1 = fdot2p(A1.w, w1h[3], z1);
        z1 = fdot2p(C1.x, w1h[4], z1); z1 = fdot2p(C1.y, w1h[5], z1);

        float p0 = fmaxf(z0, 0.f) * wp2;
        float p1 = fmaxf(z1, 0.f) * wp2;
        p0 = head_reduce(p0);
        p1 = head_reduce(p1);
        p0 += __shfl_xor(p0, 16); p1 += __shfl_xor(p1, 16);
        p0 += __shfl_xor(p0, 32); p1 += __shfl_xor(p1, 32);
        if (lane == 0) {
            out[3072 + e0i] = p0 + b2;
            out[3072 + e1i] = p1 + b2;
        }
    }
}

// ---------------- host ----------------

extern "C" void kernel_launch(void* const* d_in, const int* in_sizes, int n_in,
                              void* d_out, int out_size, void* d_ws, size_t ws_size,
                              hipStream_t stream)
{
    const float* x     = (const float*)d_in[0];
    const float* eattr = (const float*)d_in[1];
    const int*   eidx  = (const int*)d_in[2];
    const int*   batch = (const int*)d_in[3];
    const float* Win   = (const float*)d_in[4];
    const float* bin   = (const float*)d_in[5];
    const float* Wl    = (const float*)d_in[6];
    const float* Wr    = (const float*)d_in[7];
    const float* We    = (const float*)d_in[8];
    const float* att   = (const float*)d_in[9];
    const float* bconv = (const float*)d_in[10];
    const float* bnsc  = (const float*)d_in[11];
    const float* bnbi  = (const float*)d_in[12];
    const float* Wv1   = (const float*)d_in[13];
    const float* bv1   = (const float*)d_in[14];
    const float* Wv2   = (const float*)d_in[15];
    const float* bv2   = (const float*)d_in[16];
    const float* Wp1   = (const float*)d_in[17];
    const float* bp1   = (const float*)d_in[18];
    const float* Wp2   = (const float*)d_in[19];
    const float* bp2   = (const float*)d_in[20];
    float* out = (float*)d_out;

    const int* src0 = eidx;
    const int* dst0 = eidx + EE;

    const size_t NH = (size_t)NN * 128;
    float* ws = (float*)d_ws;
    float* h  = ws;                    // N*128 fp32
    float* g  = h + NH;                // N*128 fp32
    unsigned short* xlb = (unsigned short*)(g + NH);        // N*128 bf16 (reused as policy P)
    unsigned short* xrb = xlb + NH;                          // N*128 bf16
    unsigned short* eaCSR = xrb + NH;                        // EPX*16 f16 (32B/edge, padded)
    unsigned short* eaOrd = eaCSR + (size_t)EPX * 16;        // EE*16 f16 (edge order)
    int* rowptr = (int*)(eaOrd + (size_t)EE * 16);           // N+1
    int* csr_src = rowptr + (NN + 1);                        // EPX (byte offsets)
    // --- zeroed region (one memset) ---
    int* deg  = csr_src + EPX;         // N
    int* fill = deg + NN;              // N
    float* bnstat = (float*)(fill + NN);        // 8 layers * NSLOT * 256
    float* pooled = bnstat + 8 * NSLOT * 256;   // G*128
    float* cnt    = pooled + (size_t)GG * 128;  // G
    size_t zero_elems = (size_t)NN + NN + 8 * NSLOT * 256 + (size_t)GG * 128 + GG;
    // --- MFMA-swizzled weights (fully rewritten each launch) ---
    unsigned short* wg = (unsigned short*)(cnt + GG);   // 8*32768
    unsigned short* wp = wg + 8 * 32768;                // 16384

    hipMemsetAsync(deg, 0, zero_elems * sizeof(float), stream);

    // CSR build + weight prep
    k_deg<<<EE / 256, 256, 0, stream>>>(dst0, deg);
    k_scan<<<1, 1024, 0, stream>>>(deg, rowptr);
    k_scatter<<<EPX / 256, 256, 0, stream>>>(src0, dst0, eattr, rowptr, deg, fill,
                                             csr_src, eaCSR, eaOrd);
    k_selfattr<<<(NN * 16) / 256, 256, 0, stream>>>(rowptr, eaCSR);
    k_wprep<<<136, 256, 0, stream>>>(Wl, Wr, Wp1, wg, wp);

    // input layer
    k_input<<<NN / 16, 256, 0, stream>>>(x, Win, bin, h);

    // 8 GATv2 + BN layers
    // even l>=2: previous odd layer's BN+res+relu fused into the GEMM A-load (writes h)
    // odd l: previous even layer's BN+relu fused into the GEMM A-load
    // layer 7: standalone bnapply for the final h
    for (int l = 0; l < 8; l++) {
        float* bs = bnstat + (size_t)l * NSLOT * 256;
        if (l == 0) {
            k_gemm_gat<<<NN / 64, 256, 0, stream>>>(h, wg, xlb, xrb);
        } else if (l % 2 == 1) {
            float* bsp = bnstat + (size_t)(l - 1) * NSLOT * 256;
            k_gemm_gat_bn<<<NN / 64, 256, 0, stream>>>(g, bsp,
                                                       bnsc + (size_t)(l - 1) * 128,
                                                       bnbi + (size_t)(l - 1) * 128,
                                                       wg + (size_t)l * 32768, xlb, xrb);
        } else {
            float* bsp = bnstat + (size_t)(l - 1) * NSLOT * 256;
            k_gemm_gat_bnres<<<NN / 64, 256, 0, stream>>>(g, bsp,
                                                          bnsc + (size_t)(l - 1) * 128,
                                                          bnbi + (size_t)(l - 1) * 128,
                                                          h, wg + (size_t)l * 32768, xlb, xrb);
        }
        k_gat<<<NN / 16, 256, 0, stream>>>(xlb, xrb, eaCSR, rowptr, csr_src,
                                           We + (size_t)l * 1536, att + (size_t)l * 128,
                                           bconv + (size_t)l * 128, g, bs);
        if (l == 7) {
            k_bnapply_res_relu<<<(NN * 128 / 4) / 256, 256, 0, stream>>>(
                (const float4*)g, bs, bnsc + (size_t)l * 128, bnbi + (size_t)l * 128,
                (float4*)h);
        }
    }

    // pooling + value head
    k_pool<<<NN / 128, 128, 0, stream>>>(h, batch, pooled, cnt);
    k_value<<<GG, 64, 0, stream>>>(pooled, cnt, Wv1, bv1, Wv2, bv2, out);

    // policy head (P stored bf16 in xlb; f16 edge-ordered attrs)
    unsigned short* P = xlb;
    k_gemm_pol<<<NN / 64, 256, 0, stream>>>(h, wp, P);
    k_policy<<<NN / 4, 256, 0, stream>>>(P, eaOrd, src0, dst0,
                                         Wp1 + 256 * 64, bp1, Wp2, bp2, out);
}